// Round 1
// baseline (846.211 us; speedup 1.0000x reference)
//
#include <hip/hip_runtime.h>
#include <hip/hip_bf16.h>
#include <math.h>

#define FEATN 12544
#define NIMG 1024

// ws float offsets
#define OFF_WT1 0
#define OFF_WT2 2048
#define OFF_H1   (OFF_WT2 + 32768)                 // 34816
#define OFF_FEAT (OFF_H1 + 1024*28800)             // +29491200
#define OFF_U    (OFF_FEAT + 1024*12544)           // +12845056
#define OFF_PART (OFF_U + 16*64*128)               // +131072
#define OFF_HID  (OFF_PART + 16*1024*128)          // +2097152
#define WS_FLOATS (OFF_HID + 1024)

// ---------------- weight transpose: oc-innermost layouts ----------------
__global__ void prep_weights(const float* __restrict__ w1, const float* __restrict__ w2,
                             float* __restrict__ ws) {
    int i = blockIdx.x * blockDim.x + threadIdx.x;
    if (i < 48 * 32) {              // wt1[r*32+oc] = w1[oc*48+r], r=c*16+ky*4+kx
        int oc = i & 31, r = i >> 5;
        ws[OFF_WT1 + i] = w1[oc * 48 + r];
    }
    if (i < 512 * 64) {             // wt2[r*64+oc] = w2[oc*512+r], r=ic*16+ky*4+kx
        int oc = i & 63, r = i >> 6;
        ws[OFF_WT2 + i] = w2[oc * 512 + r];
    }
}

// ---------------- conv1: (1024,3,62,62) -> (1024,32,30,30), relu ----------------
__global__ __launch_bounds__(256) void conv1_kernel(const float* __restrict__ x,
                                                    const float* __restrict__ b1,
                                                    const float* __restrict__ wt1,
                                                    float* __restrict__ h1) {
    __shared__ float xs[3 * 62 * 62];
    int img = blockIdx.x;
    const float* xg = x + (size_t)img * 11532;
    for (int idx = threadIdx.x; idx < 11532; idx += 256) xs[idx] = xg[idx];
    __syncthreads();
    for (int sp = threadIdx.x; sp < 900; sp += 256) {
        int oy = sp / 30, ox = sp % 30;
        float acc[32];
        #pragma unroll
        for (int oc = 0; oc < 32; ++oc) acc[oc] = b1[oc];
        for (int c = 0; c < 3; ++c)
            for (int ky = 0; ky < 4; ++ky) {
                const float* row = &xs[c * 3844 + (2 * oy + ky) * 62 + 2 * ox];
                #pragma unroll
                for (int kx = 0; kx < 4; ++kx) {
                    float xv = row[kx];
                    const float* wrow = wt1 + (c * 16 + ky * 4 + kx) * 32;
                    #pragma unroll
                    for (int oc = 0; oc < 32; ++oc) acc[oc] += xv * wrow[oc];
                }
            }
        float* og = h1 + (size_t)img * 28800 + sp;
        #pragma unroll
        for (int oc = 0; oc < 32; ++oc) og[oc * 900] = fmaxf(acc[oc], 0.f);
    }
}

// ---------------- conv2: (1024,32,30,30) -> feat (1024, 64*14*14), relu ----------------
__global__ __launch_bounds__(256) void conv2_kernel(const float* __restrict__ h1,
                                                    const float* __restrict__ b2,
                                                    const float* __restrict__ wt2,
                                                    float* __restrict__ feat) {
    __shared__ float xs[8 * 900];
    int img = blockIdx.x;
    const float* xg = h1 + (size_t)img * 28800;
    int sp = threadIdx.x;            // 0..195 active for compute
    int oy = sp / 14, ox = sp % 14;
    float acc[64];
    #pragma unroll
    for (int oc = 0; oc < 64; ++oc) acc[oc] = b2[oc];
    for (int ch = 0; ch < 32; ch += 8) {
        __syncthreads();
        for (int idx = threadIdx.x; idx < 7200; idx += 256) xs[idx] = xg[ch * 900 + idx];
        __syncthreads();
        if (sp < 196) {
            for (int ic = 0; ic < 8; ++ic)
                for (int ky = 0; ky < 4; ++ky) {
                    const float* row = &xs[ic * 900 + (2 * oy + ky) * 30 + 2 * ox];
                    #pragma unroll
                    for (int kx = 0; kx < 4; ++kx) {
                        float xv = row[kx];
                        const float* wrow = wt2 + ((ch + ic) * 16 + ky * 4 + kx) * 64;
                        #pragma unroll
                        for (int oc = 0; oc < 64; ++oc) acc[oc] += xv * wrow[oc];
                    }
                }
        }
    }
    if (sp < 196) {
        float* og = feat + (size_t)img * 12544 + sp;
        #pragma unroll
        for (int oc = 0; oc < 64; ++oc) og[oc * 196] = fmaxf(acc[oc], 0.f);
    }
}

// ---------------- u = feat @ W_in, split-K partials ----------------
__global__ __launch_bounds__(256) void gemm_u(const float* __restrict__ feat,
                                              const float* __restrict__ Wbb,
                                              float* __restrict__ part) {
    __shared__ float As[16 * 16];
    __shared__ float Bs[16 * 128];
    int m0 = blockIdx.x * 16;        // 64 M-tiles
    int k0 = blockIdx.y * 784;       // 16 K-splits
    int col = threadIdx.x & 127;
    int rh = threadIdx.x >> 7;       // 0/1
    float acc[8] = {0.f, 0.f, 0.f, 0.f, 0.f, 0.f, 0.f, 0.f};
    for (int kc = 0; kc < 784; kc += 16) {
        __syncthreads();
        {
            int r = threadIdx.x >> 4, kk = threadIdx.x & 15;
            As[r * 16 + kk] = feat[(size_t)(m0 + r) * FEATN + k0 + kc + kk];
        }
        for (int idx = threadIdx.x; idx < 2048; idx += 256) {
            int kk = idx >> 7, c2 = idx & 127;
            Bs[idx] = Wbb[(size_t)(k0 + kc + kk) * 128 + c2];
        }
        __syncthreads();
        #pragma unroll
        for (int kk = 0; kk < 16; ++kk) {
            float bv = Bs[kk * 128 + col];
            #pragma unroll
            for (int r = 0; r < 8; ++r)
                acc[r] += As[(rh * 8 + r) * 16 + kk] * bv;
        }
    }
    float* pg = part + (size_t)blockIdx.y * 131072 + (size_t)m0 * 128;
    #pragma unroll
    for (int r = 0; r < 8; ++r) pg[(rh * 8 + r) * 128 + col] = acc[r];
}

__global__ void reduce_u(const float* __restrict__ part, const float* __restrict__ bbb,
                         float* __restrict__ u) {
    int i = blockIdx.x * 256 + threadIdx.x;   // 131072 total
    float s = bbb[i & 127];
    #pragma unroll
    for (int ks = 0; ks < 16; ++ks) s += part[ks * 131072 + i];
    u[i] = s;
}

// ---------------- liquid RNN scan: 16 independent batches ----------------
__global__ __launch_bounds__(128) void rnn_kernel(const float* __restrict__ u,
                                                  const float* __restrict__ Wbb,
                                                  const float* __restrict__ Wff1, const float* __restrict__ bff1,
                                                  const float* __restrict__ Wff2, const float* __restrict__ bff2,
                                                  const float* __restrict__ Wta,  const float* __restrict__ bta,
                                                  const float* __restrict__ Wtb,  const float* __restrict__ btb,
                                                  float* __restrict__ hid_out) {
    __shared__ float hid[64];
    __shared__ float zs[128];
    __shared__ float fs[2][64];
    __shared__ float ts[2][64];
    int b = blockIdx.x;
    int tid = threadIdx.x;
    if (tid < 64) hid[tid] = 0.f;
    __syncthreads();
    const float* Wh = Wbb + (size_t)FEATN * 128;
    int i = tid & 63, grp = tid >> 6;
    const float* Wf = grp ? Wff2 : Wff1;
    const float* Wt = grp ? Wtb : Wta;
    for (int t = 0; t < 64; ++t) {
        float a = u[((size_t)b * 64 + t) * 128 + tid];
        #pragma unroll 8
        for (int j = 0; j < 64; ++j) a += hid[j] * Wh[j * 128 + tid];
        zs[tid] = 1.7159f * tanhf(0.666f * a);
        __syncthreads();
        float sf = 0.f, st = 0.f;
        #pragma unroll 8
        for (int k = 0; k < 128; ++k) {
            float zv = zs[k];
            sf += zv * Wf[k * 64 + i];
            st += zv * Wt[k * 64 + i];
        }
        fs[grp][i] = sf;
        ts[grp][i] = st;
        __syncthreads();
        if (tid < 64) {
            float ff1 = tanhf(fs[0][i] + bff1[i]);
            float ff2 = tanhf(fs[1][i] + bff2[i]);
            float tt = ts[0][i] + bta[i] + ts[1][i] + btb[i];
            tt = 1.f / (1.f + expf(-tt));
            hid[i] = ff1 * (1.f - tt) + tt * ff2;
        }
        __syncthreads();
    }
    if (tid < 64) hid_out[b * 64 + tid] = hid[tid];
}

// ---------------- head ----------------
__global__ void head_kernel(const float* __restrict__ hid, const float* __restrict__ Wout,
                            const float* __restrict__ bout, float* __restrict__ out) {
    int tid = threadIdx.x;           // 128 = 16*8
    int b = tid >> 3, a = tid & 7;
    float s = bout[a];
    #pragma unroll
    for (int j = 0; j < 64; ++j) s += hid[b * 64 + j] * Wout[j * 8 + a];
    out[tid] = s;
}

extern "C" void kernel_launch(void* const* d_in, const int* in_sizes, int n_in,
                              void* d_out, int out_size, void* d_ws, size_t ws_size,
                              hipStream_t stream) {
    const float* x    = (const float*)d_in[0];
    const float* w1   = (const float*)d_in[1];
    const float* b1   = (const float*)d_in[2];
    const float* w2   = (const float*)d_in[3];
    const float* b2   = (const float*)d_in[4];
    const float* Wbb  = (const float*)d_in[5];
    const float* bbb  = (const float*)d_in[6];
    const float* Wff1 = (const float*)d_in[7];
    const float* bff1 = (const float*)d_in[8];
    const float* Wff2 = (const float*)d_in[9];
    const float* bff2 = (const float*)d_in[10];
    const float* Wta  = (const float*)d_in[11];
    const float* bta  = (const float*)d_in[12];
    const float* Wtb  = (const float*)d_in[13];
    const float* btb  = (const float*)d_in[14];
    const float* Wout = (const float*)d_in[15];
    const float* bout = (const float*)d_in[16];

    if (ws_size < (size_t)WS_FLOATS * sizeof(float)) return;  // scratch too small -> loud fail

    float* ws   = (float*)d_ws;
    float* wt1  = ws + OFF_WT1;
    float* wt2  = ws + OFF_WT2;
    float* h1   = ws + OFF_H1;
    float* feat = ws + OFF_FEAT;
    float* u    = ws + OFF_U;
    float* part = ws + OFF_PART;
    float* hid  = ws + OFF_HID;

    prep_weights<<<128, 256, 0, stream>>>(w1, w2, ws);
    conv1_kernel<<<1024, 256, 0, stream>>>(x, b1, wt1, h1);
    conv2_kernel<<<1024, 256, 0, stream>>>(h1, b2, wt2, feat);
    gemm_u<<<dim3(64, 16), 256, 0, stream>>>(feat, Wbb, part);
    reduce_u<<<512, 256, 0, stream>>>(part, bbb, u);
    rnn_kernel<<<16, 128, 0, stream>>>(u, Wbb, Wff1, bff1, Wff2, bff2, Wta, bta, Wtb, btb, hid);
    head_kernel<<<1, 128, 0, stream>>>(hid, Wout, bout, (float*)d_out);
}

// Round 2
// 650.909 us; speedup vs baseline: 1.3000x; 1.3000x over previous
//
#include <hip/hip_runtime.h>
#include <hip/hip_bf16.h>
#include <math.h>

#define FEATN 12544
#define NIMG 1024

// ws float offsets
#define OFF_WT1 0
#define OFF_WT2 2048
#define OFF_H1   (OFF_WT2 + 32768)                 // 34816
#define OFF_FEAT (OFF_H1 + 1024*28800)             // +29491200
#define OFF_U    (OFF_FEAT + 1024*12544)           // +12845056
#define OFF_PART (OFF_U + 16*64*128)               // +131072
#define OFF_HID  (OFF_PART + 16*1024*128)          // +2097152
#define WS_FLOATS (OFF_HID + 1024)

__device__ __forceinline__ float fast_tanh(float x) {
    x = fminf(fmaxf(x, -15.f), 15.f);
    float e = __expf(2.f * x);                  // v_exp_f32-based
    return (e - 1.f) * __builtin_amdgcn_rcpf(e + 1.f);
}
__device__ __forceinline__ float fast_sigmoid(float x) {
    x = fminf(fmaxf(x, -30.f), 30.f);
    return __builtin_amdgcn_rcpf(1.f + __expf(-x));
}

// ---------------- weight transpose: oc-innermost layouts ----------------
__global__ void prep_weights(const float* __restrict__ w1, const float* __restrict__ w2,
                             float* __restrict__ ws) {
    int i = blockIdx.x * blockDim.x + threadIdx.x;
    if (i < 48 * 32) {              // wt1[r*32+oc] = w1[oc*48+r], r=c*16+ky*4+kx
        int oc = i & 31, r = i >> 5;
        ws[OFF_WT1 + i] = w1[oc * 48 + r];
    }
    if (i < 512 * 64) {             // wt2[r*64+oc] = w2[oc*512+r], r=ic*16+ky*4+kx
        int oc = i & 63, r = i >> 6;
        ws[OFF_WT2 + i] = w2[oc * 512 + r];
    }
}

// ---------------- conv1: (1024,3,62,62) -> (1024,32,30,30), relu ----------------
__global__ __launch_bounds__(256) void conv1_kernel(const float* __restrict__ x,
                                                    const float* __restrict__ b1,
                                                    const float* __restrict__ wt1,
                                                    float* __restrict__ h1) {
    __shared__ float xs[3 * 62 * 62];
    int img = blockIdx.x;
    const float* xg = x + (size_t)img * 11532;
    for (int idx = threadIdx.x; idx < 11532; idx += 256) xs[idx] = xg[idx];
    __syncthreads();
    for (int sp = threadIdx.x; sp < 900; sp += 256) {
        int oy = sp / 30, ox = sp % 30;
        float acc[32];
        #pragma unroll
        for (int oc = 0; oc < 32; ++oc) acc[oc] = b1[oc];
        for (int c = 0; c < 3; ++c)
            for (int ky = 0; ky < 4; ++ky) {
                const float* row = &xs[c * 3844 + (2 * oy + ky) * 62 + 2 * ox];
                #pragma unroll
                for (int kx = 0; kx < 4; ++kx) {
                    float xv = row[kx];
                    const float* wrow = wt1 + (c * 16 + ky * 4 + kx) * 32;
                    #pragma unroll
                    for (int oc = 0; oc < 32; ++oc) acc[oc] += xv * wrow[oc];
                }
            }
        float* og = h1 + (size_t)img * 28800 + sp;
        #pragma unroll
        for (int oc = 0; oc < 32; ++oc) og[oc * 900] = fmaxf(acc[oc], 0.f);
    }
}

// ---------------- conv2: (1024,32,30,30) -> feat (1024, 64*14*14), relu ----------------
__global__ __launch_bounds__(256) void conv2_kernel(const float* __restrict__ h1,
                                                    const float* __restrict__ b2,
                                                    const float* __restrict__ wt2,
                                                    float* __restrict__ feat) {
    __shared__ float xs[8 * 900];
    int img = blockIdx.x;
    const float* xg = h1 + (size_t)img * 28800;
    int sp = threadIdx.x;            // 0..195 active for compute
    int oy = sp / 14, ox = sp % 14;
    float acc[64];
    #pragma unroll
    for (int oc = 0; oc < 64; ++oc) acc[oc] = b2[oc];
    for (int ch = 0; ch < 32; ch += 8) {
        __syncthreads();
        for (int idx = threadIdx.x; idx < 7200; idx += 256) xs[idx] = xg[ch * 900 + idx];
        __syncthreads();
        if (sp < 196) {
            for (int ic = 0; ic < 8; ++ic)
                for (int ky = 0; ky < 4; ++ky) {
                    const float* row = &xs[ic * 900 + (2 * oy + ky) * 30 + 2 * ox];
                    #pragma unroll
                    for (int kx = 0; kx < 4; ++kx) {
                        float xv = row[kx];
                        const float* wrow = wt2 + ((ch + ic) * 16 + ky * 4 + kx) * 64;
                        #pragma unroll
                        for (int oc = 0; oc < 64; ++oc) acc[oc] += xv * wrow[oc];
                    }
                }
        }
    }
    if (sp < 196) {
        float* og = feat + (size_t)img * 12544 + sp;
        #pragma unroll
        for (int oc = 0; oc < 64; ++oc) og[oc * 196] = fmaxf(acc[oc], 0.f);
    }
}

// ---------------- u = feat @ W_in, split-K partials ----------------
__global__ __launch_bounds__(256) void gemm_u(const float* __restrict__ feat,
                                              const float* __restrict__ Wbb,
                                              float* __restrict__ part) {
    __shared__ float As[16 * 16];
    __shared__ float Bs[16 * 128];
    int m0 = blockIdx.x * 16;        // 64 M-tiles
    int k0 = blockIdx.y * 784;       // 16 K-splits
    int col = threadIdx.x & 127;
    int rh = threadIdx.x >> 7;       // 0/1
    float acc[8] = {0.f, 0.f, 0.f, 0.f, 0.f, 0.f, 0.f, 0.f};
    for (int kc = 0; kc < 784; kc += 16) {
        __syncthreads();
        {
            int r = threadIdx.x >> 4, kk = threadIdx.x & 15;
            As[r * 16 + kk] = feat[(size_t)(m0 + r) * FEATN + k0 + kc + kk];
        }
        for (int idx = threadIdx.x; idx < 2048; idx += 256) {
            int kk = idx >> 7, c2 = idx & 127;
            Bs[idx] = Wbb[(size_t)(k0 + kc + kk) * 128 + c2];
        }
        __syncthreads();
        #pragma unroll
        for (int kk = 0; kk < 16; ++kk) {
            float bv = Bs[kk * 128 + col];
            #pragma unroll
            for (int r = 0; r < 8; ++r)
                acc[r] += As[(rh * 8 + r) * 16 + kk] * bv;
        }
    }
    float* pg = part + (size_t)blockIdx.y * 131072 + (size_t)m0 * 128;
    #pragma unroll
    for (int r = 0; r < 8; ++r) pg[(rh * 8 + r) * 128 + col] = acc[r];
}

__global__ void reduce_u(const float* __restrict__ part, const float* __restrict__ bbb,
                         float* __restrict__ u) {
    int i = blockIdx.x * 256 + threadIdx.x;   // 131072 total
    float s = bbb[i & 127];
    #pragma unroll
    for (int ks = 0; ks < 16; ++ks) s += part[ks * 131072 + i];
    u[i] = s;
}

// ---------------- liquid RNN scan: 16 independent batches ----------------
// 256 threads/block. Weights live in REGISTERS (fully unrolled, compile-time
// indices -> VGPRs, no scratch). u slab (32KB) staged in LDS once.
// 3 barriers per timestep; dependent chains split 4-way.
__global__ __launch_bounds__(256, 1) void rnn_kernel(const float* __restrict__ u,
                                                  const float* __restrict__ Wbb,
                                                  const float* __restrict__ Wff1, const float* __restrict__ bff1,
                                                  const float* __restrict__ Wff2, const float* __restrict__ bff2,
                                                  const float* __restrict__ Wta,  const float* __restrict__ bta,
                                                  const float* __restrict__ Wtb,  const float* __restrict__ btb,
                                                  float* __restrict__ hid_out) {
    __shared__ float u_s[64 * 128];
    __shared__ float hid_s[64];
    __shared__ float zs[128];
    __shared__ float fsts[4][64];
    int b = blockIdx.x;
    int tid = threadIdx.x;

    // stage u for this batch into LDS (coalesced float4)
    {
        const float4* ug = (const float4*)(u + (size_t)b * 8192);
        float4* us4 = (float4*)u_s;
        for (int idx = tid; idx < 2048; idx += 256) us4[idx] = ug[idx];
    }

    // weights -> registers
    const float* Wh = Wbb + (size_t)FEATN * 128;
    float wh[64];
    if (tid < 128) {
        #pragma unroll
        for (int j = 0; j < 64; ++j) wh[j] = Wh[j * 128 + tid];   // coalesced per j
    }
    int grp = tid >> 6, i = tid & 63;
    const float* Wg = (grp == 0) ? Wff1 : (grp == 1) ? Wff2 : (grp == 2) ? Wta : Wtb;
    float wc[128];
    #pragma unroll
    for (int k = 0; k < 128; ++k) wc[k] = Wg[k * 64 + i];         // coalesced per k

    float bf1 = 0.f, bf2 = 0.f, bts = 0.f;
    if (tid < 64) {
        bf1 = bff1[tid]; bf2 = bff2[tid]; bts = bta[tid] + btb[tid];
        hid_s[tid] = 0.f;
    }
    __syncthreads();

    for (int t = 0; t < 64; ++t) {
        if (tid < 128) {
            float a0 = u_s[t * 128 + tid], a1 = 0.f, a2 = 0.f, a3 = 0.f;
            #pragma unroll
            for (int j = 0; j < 64; j += 4) {
                a0 += hid_s[j    ] * wh[j    ];
                a1 += hid_s[j + 1] * wh[j + 1];
                a2 += hid_s[j + 2] * wh[j + 2];
                a3 += hid_s[j + 3] * wh[j + 3];
            }
            float a = (a0 + a1) + (a2 + a3);
            zs[tid] = 1.7159f * fast_tanh(0.666f * a);
        }
        __syncthreads();
        {
            float s0 = 0.f, s1 = 0.f, s2 = 0.f, s3 = 0.f;
            #pragma unroll
            for (int k = 0; k < 128; k += 4) {
                s0 += zs[k    ] * wc[k    ];
                s1 += zs[k + 1] * wc[k + 1];
                s2 += zs[k + 2] * wc[k + 2];
                s3 += zs[k + 3] * wc[k + 3];
            }
            fsts[grp][i] = (s0 + s1) + (s2 + s3);
        }
        __syncthreads();
        if (tid < 64) {
            float ff1 = fast_tanh(fsts[0][tid] + bf1);
            float ff2 = fast_tanh(fsts[1][tid] + bf2);
            float tt  = fast_sigmoid(fsts[2][tid] + fsts[3][tid] + bts);
            hid_s[tid] = ff1 * (1.f - tt) + tt * ff2;
        }
        __syncthreads();
    }
    if (tid < 64) hid_out[b * 64 + tid] = hid_s[tid];
}

// ---------------- head ----------------
__global__ void head_kernel(const float* __restrict__ hid, const float* __restrict__ Wout,
                            const float* __restrict__ bout, float* __restrict__ out) {
    int tid = threadIdx.x;           // 128 = 16*8
    int b = tid >> 3, a = tid & 7;
    float s = bout[a];
    #pragma unroll
    for (int j = 0; j < 64; ++j) s += hid[b * 64 + j] * Wout[j * 8 + a];
    out[tid] = s;
}

extern "C" void kernel_launch(void* const* d_in, const int* in_sizes, int n_in,
                              void* d_out, int out_size, void* d_ws, size_t ws_size,
                              hipStream_t stream) {
    const float* x    = (const float*)d_in[0];
    const float* w1   = (const float*)d_in[1];
    const float* b1   = (const float*)d_in[2];
    const float* w2   = (const float*)d_in[3];
    const float* b2   = (const float*)d_in[4];
    const float* Wbb  = (const float*)d_in[5];
    const float* bbb  = (const float*)d_in[6];
    const float* Wff1 = (const float*)d_in[7];
    const float* bff1 = (const float*)d_in[8];
    const float* Wff2 = (const float*)d_in[9];
    const float* bff2 = (const float*)d_in[10];
    const float* Wta  = (const float*)d_in[11];
    const float* bta  = (const float*)d_in[12];
    const float* Wtb  = (const float*)d_in[13];
    const float* btb  = (const float*)d_in[14];
    const float* Wout = (const float*)d_in[15];
    const float* bout = (const float*)d_in[16];

    if (ws_size < (size_t)WS_FLOATS * sizeof(float)) return;  // scratch too small -> loud fail

    float* ws   = (float*)d_ws;
    float* wt1  = ws + OFF_WT1;
    float* wt2  = ws + OFF_WT2;
    float* h1   = ws + OFF_H1;
    float* feat = ws + OFF_FEAT;
    float* u    = ws + OFF_U;
    float* part = ws + OFF_PART;
    float* hid  = ws + OFF_HID;

    prep_weights<<<128, 256, 0, stream>>>(w1, w2, ws);
    conv1_kernel<<<1024, 256, 0, stream>>>(x, b1, wt1, h1);
    conv2_kernel<<<1024, 256, 0, stream>>>(h1, b2, wt2, feat);
    gemm_u<<<dim3(64, 16), 256, 0, stream>>>(feat, Wbb, part);
    reduce_u<<<512, 256, 0, stream>>>(part, bbb, u);
    rnn_kernel<<<16, 256, 0, stream>>>(u, Wbb, Wff1, bff1, Wff2, bff2, Wta, bta, Wtb, btb, hid);
    head_kernel<<<1, 128, 0, stream>>>(hid, Wout, bout, (float*)d_out);
}

// Round 4
// 333.286 us; speedup vs baseline: 2.5390x; 1.9530x over previous
//
#include <hip/hip_runtime.h>
#include <hip/hip_bf16.h>
#include <math.h>

#define FEATN 12544
#define NIMG 1024

typedef __attribute__((ext_vector_type(8))) short short8;
typedef __attribute__((ext_vector_type(4))) float f32x4;

// ---- ws byte offsets (all sizes in BYTES; bf16 regions are 2 B/elem) ----
#define OFF_WT1   0            //  1536 f32   =     6144 B
#define OFF_W2F   6144         //  32768 bf16 =    65536 B   conv2 B-frag table
#define OFF_WBBF  71680        //  1605632 bf16 = 3211264 B  gemm_u B-frag table
#define OFF_H1B   3282944      //  1024*28800 bf16 = 58982400 B
#define OFF_FEATB 62265344     //  1024*12544 bf16 = 25690112 B
#define OFF_U     87955456     //  131072 f32 = 524288 B
#define OFF_PART  88479744     //  28*131072 f32 = 14680064 B
#define OFF_HID   103159808    //  1024 f32 = 4096 B
#define WS_BYTES  103163904

__device__ __forceinline__ unsigned short f2bf(float v) {
    union { float f; unsigned int u; } c; c.f = v;
    unsigned int r = c.u + 0x7FFFu + ((c.u >> 16) & 1u);   // RNE
    return (unsigned short)(r >> 16);
}

__device__ __forceinline__ float fast_tanh(float x) {
    x = fminf(fmaxf(x, -15.f), 15.f);
    float e = __expf(2.f * x);
    return (e - 1.f) * __builtin_amdgcn_rcpf(e + 1.f);
}
__device__ __forceinline__ float fast_sigmoid(float x) {
    x = fminf(fmaxf(x, -30.f), 30.f);
    return __builtin_amdgcn_rcpf(1.f + __expf(-x));
}

// ---------------- prep: conv1 weight transpose (fp32, oc-innermost) ----------------
__global__ void prep_wt1(const float* __restrict__ w1, float* __restrict__ wt1) {
    int i = blockIdx.x * blockDim.x + threadIdx.x;
    if (i < 48 * 32) { int oc = i & 31, r = i >> 5; wt1[i] = w1[oc * 48 + r]; }
}

// ---------------- prep: conv2 weights -> MFMA B-frag layout (bf16) ----------------
// w2f[((nt*16+kstep)*64+lane)*8+j] = w2[oc*512 + ic*16 + ky*4 + kx]
//   oc = nt*16+(lane&15), ic = 2*kstep+(j>>2), ky = lane>>4, kx = j&3
__global__ void prep_w2f(const float* __restrict__ w2, unsigned short* __restrict__ w2f) {
    int i = blockIdx.x * blockDim.x + threadIdx.x;   // 32768
    int j = i & 7, lane = (i >> 3) & 63, kstep = (i >> 9) & 15, nt = i >> 13;
    int oc = nt * 16 + (lane & 15);
    int ic = 2 * kstep + (j >> 2);
    int ky = lane >> 4, kx = j & 3;
    w2f[i] = f2bf(w2[oc * 512 + ic * 16 + ky * 4 + kx]);
}

// ---------------- prep: Wbb -> MFMA B-frag layout (bf16) ----------------
// Wbbf[((kstep*8+nt)*64+lane)*8+j] = Wbb[(kstep*32+(lane>>4)*8+j)*128 + nt*16+(lane&15)]
__global__ void prep_wbbf(const float* __restrict__ Wbb, unsigned short* __restrict__ Wbbf) {
    int i = blockIdx.x * blockDim.x + threadIdx.x;   // 1605632
    int j = i & 7, lane = (i >> 3) & 63, nt = (i >> 9) & 7, kstep = i >> 12;
    int f = kstep * 32 + (lane >> 4) * 8 + j;
    int col = nt * 16 + (lane & 15);
    Wbbf[i] = f2bf(Wbb[(size_t)f * 128 + col]);
}

// ---------------- conv1: (1024,3,62,62) -> h1b bf16 (1024,32,900), relu ----------------
__global__ __launch_bounds__(256) void conv1_kernel(const float* __restrict__ x,
                                                    const float* __restrict__ b1,
                                                    const float* __restrict__ wt1,
                                                    unsigned short* __restrict__ h1b) {
    __shared__ float xs[3 * 62 * 62];
    int img = blockIdx.x;
    const float* xg = x + (size_t)img * 11532;
    for (int idx = threadIdx.x; idx < 11532; idx += 256) xs[idx] = xg[idx];
    __syncthreads();
    for (int sp = threadIdx.x; sp < 900; sp += 256) {
        int oy = sp / 30, ox = sp % 30;
        float acc[32];
        #pragma unroll
        for (int oc = 0; oc < 32; ++oc) acc[oc] = b1[oc];
        for (int c = 0; c < 3; ++c)
            for (int ky = 0; ky < 4; ++ky) {
                const float* row = &xs[c * 3844 + (2 * oy + ky) * 62 + 2 * ox];
                #pragma unroll
                for (int kx = 0; kx < 4; ++kx) {
                    float xv = row[kx];
                    const float* wrow = wt1 + (c * 16 + ky * 4 + kx) * 32;
                    #pragma unroll
                    for (int oc = 0; oc < 32; ++oc) acc[oc] += xv * wrow[oc];
                }
            }
        unsigned short* og = h1b + (size_t)img * 28800 + sp;
        #pragma unroll
        for (int oc = 0; oc < 32; ++oc) og[oc * 900] = f2bf(fmaxf(acc[oc], 0.f));
    }
}

// ---------------- conv2 as implicit GEMM, bf16 MFMA ----------------
// Per block: 1 image. M=196 (13 tiles, clamp/mask), N=64 (4 ntiles), K=512 (16 ksteps).
// K-perm per kstep(=2 ic): lane-group g <-> ky; frag j: (j>>2)=ic offset, (j&3)=kx.
// A and B use the SAME (lane,j)->k labeling, so any internal HW K-permutation cancels.
__global__ __launch_bounds__(256) void conv2_mfma(const unsigned short* __restrict__ h1b,
                                                  const float* __restrict__ b2,
                                                  const unsigned short* __restrict__ w2f,
                                                  unsigned short* __restrict__ featb) {
    __shared__ unsigned short h1s[32 * 30 * 32];   // [ic][y][x pad 32] = 60 KB
    int img = blockIdx.x;
    int tid = threadIdx.x;
    // stage h1 image (bf16, 14400 dwords), inserting x-padding
    {
        const unsigned int* src = (const unsigned int*)(h1b + (size_t)img * 28800);
        unsigned int* dst = (unsigned int*)h1s;
        for (int d = tid; d < 14400; d += 256) {
            int ic = d / 450, r = d - ic * 450;
            int y = r / 15, x2 = r - y * 15;
            dst[(ic * 30 + y) * 16 + x2] = src[d];
        }
    }
    __syncthreads();
    int lane = tid & 63, wid = tid >> 6;
    int rowl = lane & 15, g = lane >> 4;

    f32x4 acc[4][4];
    #pragma unroll
    for (int i = 0; i < 4; ++i)
        #pragma unroll
        for (int nt = 0; nt < 4; ++nt) acc[i][nt] = (f32x4){0.f, 0.f, 0.f, 0.f};

    int dofs[4];
    #pragma unroll
    for (int i = 0; i < 4; ++i) {
        int mtile = wid + 4 * i;
        int m = mtile * 16 + rowl; if (m > 195) m = 195;
        int oy = m / 14, ox = m - oy * 14;
        int y = 2 * oy + g, x0 = 2 * ox;
        dofs[i] = y * 16 + (x0 >> 1);               // dword offset within ic-plane
    }
    const unsigned int* lds32 = (const unsigned int*)h1s;

    #pragma unroll 4
    for (int kstep = 0; kstep < 16; ++kstep) {
        short8 bfr[4];
        #pragma unroll
        for (int nt = 0; nt < 4; ++nt)
            bfr[nt] = *(const short8*)(w2f + (((nt * 16 + kstep) * 64 + lane) << 3));
        int icb = kstep * 960;                      // 2 ic-planes per kstep (480 dwords each)
        #pragma unroll
        for (int i = 0; i < 4; ++i) {
            int mtile = wid + 4 * i;
            if (mtile < 13) {
                int dof = icb + dofs[i];
                union { unsigned int u[4]; short8 s; } af;
                af.u[0] = lds32[dof];
                af.u[1] = lds32[dof + 1];
                af.u[2] = lds32[dof + 480];
                af.u[3] = lds32[dof + 481];
                #pragma unroll
                for (int nt = 0; nt < 4; ++nt)
                    acc[i][nt] = __builtin_amdgcn_mfma_f32_16x16x32_bf16(af.s, bfr[nt], acc[i][nt], 0, 0, 0);
            }
        }
    }
    // epilogue: bias + relu + bf16, feat layout [img][oc*196+sp]
    #pragma unroll
    for (int i = 0; i < 4; ++i) {
        int mtile = wid + 4 * i;
        if (mtile >= 13) continue;
        int sp0 = mtile * 16 + g * 4;
        #pragma unroll
        for (int nt = 0; nt < 4; ++nt) {
            int oc = nt * 16 + rowl;
            float bias = b2[oc];
            unsigned short pk[4];
            #pragma unroll
            for (int r = 0; r < 4; ++r)
                pk[r] = f2bf(fmaxf(acc[i][nt][r] + bias, 0.f));
            unsigned short* dstp = featb + (size_t)img * 12544 + oc * 196 + sp0;
            if (sp0 + 3 < 196) {
                *(uint2*)dstp = *(uint2*)pk;        // 8B aligned: sp0%4==0, oc*392%8==0
            } else {
                #pragma unroll
                for (int r = 0; r < 4; ++r) if (sp0 + r < 196) dstp[r] = pk[r];
            }
        }
    }
}

// ---------------- u = feat @ W_in : bf16 MFMA, split-K=28 ----------------
// grid (16, 28); block 256 = 4 waves, each wave 16 rows x 128 cols; 14 ksteps/block.
__global__ __launch_bounds__(256) void gemm_u_mfma(const unsigned short* __restrict__ featb,
                                                   const unsigned short* __restrict__ Wbbf,
                                                   float* __restrict__ part) {
    int tid = threadIdx.x, lane = tid & 63, wid = tid >> 6;
    int rowl = lane & 15, g = lane >> 4;
    int m0 = blockIdx.x * 64 + wid * 16;
    int ks0 = blockIdx.y * 14;
    f32x4 acc[8];
    #pragma unroll
    for (int nt = 0; nt < 8; ++nt) acc[nt] = (f32x4){0.f, 0.f, 0.f, 0.f};
    const unsigned short* arow = featb + (size_t)(m0 + rowl) * FEATN + g * 8;
    #pragma unroll 2
    for (int kk = 0; kk < 14; ++kk) {
        int kstep = ks0 + kk;
        short8 afr = *(const short8*)(arow + kstep * 32);
        #pragma unroll
        for (int nt = 0; nt < 8; ++nt) {
            short8 bfr = *(const short8*)(Wbbf + ((((size_t)kstep * 8 + nt) * 64 + lane) << 3));
            acc[nt] = __builtin_amdgcn_mfma_f32_16x16x32_bf16(afr, bfr, acc[nt], 0, 0, 0);
        }
    }
    float* pg = part + (size_t)blockIdx.y * 131072;
    #pragma unroll
    for (int nt = 0; nt < 8; ++nt)
        #pragma unroll
        for (int r = 0; r < 4; ++r)
            pg[(m0 + g * 4 + r) * 128 + nt * 16 + rowl] = acc[nt][r];
}

__global__ void reduce_u(const float* __restrict__ part, const float* __restrict__ bbb,
                         float* __restrict__ u) {
    int i = blockIdx.x * 256 + threadIdx.x;   // 131072 total
    float s = bbb[i & 127];
    #pragma unroll
    for (int ks = 0; ks < 28; ++ks) s += part[(size_t)ks * 131072 + i];
    u[i] = s;
}

// ---------------- liquid RNN scan ----------------
__global__ __launch_bounds__(256, 1) void rnn_kernel(const float* __restrict__ u,
                                                  const float* __restrict__ Wbb,
                                                  const float* __restrict__ Wff1, const float* __restrict__ bff1,
                                                  const float* __restrict__ Wff2, const float* __restrict__ bff2,
                                                  const float* __restrict__ Wta,  const float* __restrict__ bta,
                                                  const float* __restrict__ Wtb,  const float* __restrict__ btb,
                                                  float* __restrict__ hid_out) {
    __shared__ float u_s[64 * 128];
    __shared__ float hid_s[64];
    __shared__ float zs[128];
    __shared__ float fsts[4][64];
    int b = blockIdx.x;
    int tid = threadIdx.x;
    {
        const float4* ug = (const float4*)(u + (size_t)b * 8192);
        float4* us4 = (float4*)u_s;
        for (int idx = tid; idx < 2048; idx += 256) us4[idx] = ug[idx];
    }
    const float* Wh = Wbb + (size_t)FEATN * 128;
    float wh[64];
    if (tid < 128) {
        #pragma unroll
        for (int j = 0; j < 64; ++j) wh[j] = Wh[j * 128 + tid];
    }
    int grp = tid >> 6, i = tid & 63;
    const float* Wg = (grp == 0) ? Wff1 : (grp == 1) ? Wff2 : (grp == 2) ? Wta : Wtb;
    float wc[128];
    #pragma unroll
    for (int k = 0; k < 128; ++k) wc[k] = Wg[k * 64 + i];
    float bf1 = 0.f, bf2 = 0.f, bts = 0.f;
    if (tid < 64) {
        bf1 = bff1[tid]; bf2 = bff2[tid]; bts = bta[tid] + btb[tid];
        hid_s[tid] = 0.f;
    }
    __syncthreads();
    for (int t = 0; t < 64; ++t) {
        if (tid < 128) {
            float a0 = u_s[t * 128 + tid], a1 = 0.f, a2 = 0.f, a3 = 0.f;
            #pragma unroll
            for (int j = 0; j < 64; j += 4) {
                a0 += hid_s[j    ] * wh[j    ];
                a1 += hid_s[j + 1] * wh[j + 1];
                a2 += hid_s[j + 2] * wh[j + 2];
                a3 += hid_s[j + 3] * wh[j + 3];
            }
            float a = (a0 + a1) + (a2 + a3);
            zs[tid] = 1.7159f * fast_tanh(0.666f * a);
        }
        __syncthreads();
        {
            float s0 = 0.f, s1 = 0.f, s2 = 0.f, s3 = 0.f;
            #pragma unroll
            for (int k = 0; k < 128; k += 4) {
                s0 += zs[k    ] * wc[k    ];
                s1 += zs[k + 1] * wc[k + 1];
                s2 += zs[k + 2] * wc[k + 2];
                s3 += zs[k + 3] * wc[k + 3];
            }
            fsts[grp][i] = (s0 + s1) + (s2 + s3);
        }
        __syncthreads();
        if (tid < 64) {
            float ff1 = fast_tanh(fsts[0][tid] + bf1);
            float ff2 = fast_tanh(fsts[1][tid] + bf2);
            float tt  = fast_sigmoid(fsts[2][tid] + fsts[3][tid] + bts);
            hid_s[tid] = ff1 * (1.f - tt) + tt * ff2;
        }
        __syncthreads();
    }
    if (tid < 64) hid_out[b * 64 + tid] = hid_s[tid];
}

// ---------------- head ----------------
__global__ void head_kernel(const float* __restrict__ hid, const float* __restrict__ Wout,
                            const float* __restrict__ bout, float* __restrict__ out) {
    int tid = threadIdx.x;           // 128 = 16*8
    int b = tid >> 3, a = tid & 7;
    float s = bout[a];
    #pragma unroll
    for (int j = 0; j < 64; ++j) s += hid[b * 64 + j] * Wout[j * 8 + a];
    out[tid] = s;
}

extern "C" void kernel_launch(void* const* d_in, const int* in_sizes, int n_in,
                              void* d_out, int out_size, void* d_ws, size_t ws_size,
                              hipStream_t stream) {
    const float* x    = (const float*)d_in[0];
    const float* w1   = (const float*)d_in[1];
    const float* b1   = (const float*)d_in[2];
    const float* w2   = (const float*)d_in[3];
    const float* b2   = (const float*)d_in[4];
    const float* Wbb  = (const float*)d_in[5];
    const float* bbb  = (const float*)d_in[6];
    const float* Wff1 = (const float*)d_in[7];
    const float* bff1 = (const float*)d_in[8];
    const float* Wff2 = (const float*)d_in[9];
    const float* bff2 = (const float*)d_in[10];
    const float* Wta  = (const float*)d_in[11];
    const float* bta  = (const float*)d_in[12];
    const float* Wtb  = (const float*)d_in[13];
    const float* btb  = (const float*)d_in[14];
    const float* Wout = (const float*)d_in[15];
    const float* bout = (const float*)d_in[16];

    if (ws_size < (size_t)WS_BYTES) return;

    char* wsb = (char*)d_ws;
    float*          wt1   = (float*)(wsb + OFF_WT1);
    unsigned short* w2f   = (unsigned short*)(wsb + OFF_W2F);
    unsigned short* wbbf  = (unsigned short*)(wsb + OFF_WBBF);
    unsigned short* h1b   = (unsigned short*)(wsb + OFF_H1B);
    unsigned short* featb = (unsigned short*)(wsb + OFF_FEATB);
    float*          u     = (float*)(wsb + OFF_U);
    float*          part  = (float*)(wsb + OFF_PART);
    float*          hid   = (float*)(wsb + OFF_HID);

    prep_wt1 <<<6, 256, 0, stream>>>(w1, wt1);
    prep_w2f <<<128, 256, 0, stream>>>(w2, w2f);
    prep_wbbf<<<6272, 256, 0, stream>>>(Wbb, wbbf);
    conv1_kernel<<<1024, 256, 0, stream>>>(x, b1, wt1, h1b);
    conv2_mfma<<<1024, 256, 0, stream>>>(h1b, b2, w2f, featb);
    gemm_u_mfma<<<dim3(16, 28), 256, 0, stream>>>(featb, wbbf, part);
    reduce_u<<<512, 256, 0, stream>>>(part, bbb, u);
    rnn_kernel<<<16, 256, 0, stream>>>(u, Wbb, Wff1, bff1, Wff2, bff2, Wta, bta, Wtb, btb, hid);
    head_kernel<<<1, 128, 0, stream>>>(hid, Wout, bout, (float*)d_out);
}

// Round 5
// 198.896 us; speedup vs baseline: 4.2545x; 1.6757x over previous
//
#include <hip/hip_runtime.h>
#include <hip/hip_bf16.h>
#include <math.h>

#define FEATN 12544
#define NIMG 1024

typedef __attribute__((ext_vector_type(8))) short short8;
typedef __attribute__((ext_vector_type(4))) float f32x4;

// ---- ws byte offsets (all sizes in BYTES; bf16 regions are 2 B/elem) ----
#define OFF_W1F   0            //  2048 bf16  =     4096 B   conv1 B-frag table
#define OFF_W2F   6144         //  32768 bf16 =    65536 B   conv2 B-frag table
#define OFF_WBBF  71680        //  1605632 bf16 = 3211264 B  gemm_u B-frag table
#define OFF_H1B   3282944      //  1024*28800 bf16 = 58982400 B
#define OFF_FEATB 62265344     //  1024*12544 bf16 = 25690112 B
#define OFF_U     87955456     //  131072 f32 = 524288 B
#define OFF_PART  88479744     //  28*131072 f32 = 14680064 B
#define OFF_HID   103159808    //  1024 f32 = 4096 B
#define WS_BYTES  103163904

__device__ __forceinline__ unsigned short f2bf(float v) {
    union { float f; unsigned int u; } c; c.f = v;
    unsigned int r = c.u + 0x7FFFu + ((c.u >> 16) & 1u);   // RNE
    return (unsigned short)(r >> 16);
}

__device__ __forceinline__ float fast_tanh(float x) {
    x = fminf(fmaxf(x, -15.f), 15.f);
    float e = __expf(2.f * x);
    return (e - 1.f) * __builtin_amdgcn_rcpf(e + 1.f);
}
__device__ __forceinline__ float fast_sigmoid(float x) {
    x = fminf(fmaxf(x, -30.f), 30.f);
    return __builtin_amdgcn_rcpf(1.f + __expf(-x));
}

// ---------------- prep: conv1 weights -> MFMA B-frag layout (bf16) ----------------
// w1f[((kstep*2+nt)*64+lane)*8+j]:
//   oc = nt*16+(lane&15), ky = (lane>>4)&3, kx = j&3
//   kstep0: ic = j>>2 (0,1); kstep1: ic = 2 if (j>>2)==0 else ZERO
__global__ void prep_w1f(const float* __restrict__ w1, unsigned short* __restrict__ w1f) {
    int i = blockIdx.x * blockDim.x + threadIdx.x;   // 2048
    if (i >= 2048) return;
    int j = i & 7, lane = (i >> 3) & 63, nt = (i >> 9) & 1, kstep = (i >> 10) & 1;
    int oc = nt * 16 + (lane & 15);
    int ky = (lane >> 4) & 3, kx = j & 3;
    float v;
    if (kstep == 0) {
        int ic = j >> 2;
        v = w1[oc * 48 + ic * 16 + ky * 4 + kx];
    } else {
        v = (j >> 2) == 0 ? w1[oc * 48 + 32 + ky * 4 + kx] : 0.f;
    }
    w1f[i] = f2bf(v);
}

// ---------------- prep: conv2 weights -> MFMA B-frag layout (bf16) ----------------
// w2f[((nt*16+kstep)*64+lane)*8+j] = w2[oc*512 + ic*16 + ky*4 + kx]
//   oc = nt*16+(lane&15), ic = 2*kstep+(j>>2), ky = lane>>4, kx = j&3
__global__ void prep_w2f(const float* __restrict__ w2, unsigned short* __restrict__ w2f) {
    int i = blockIdx.x * blockDim.x + threadIdx.x;   // 32768
    int j = i & 7, lane = (i >> 3) & 63, kstep = (i >> 9) & 15, nt = i >> 13;
    int oc = nt * 16 + (lane & 15);
    int ic = 2 * kstep + (j >> 2);
    int ky = lane >> 4, kx = j & 3;
    w2f[i] = f2bf(w2[oc * 512 + ic * 16 + ky * 4 + kx]);
}

// ---------------- prep: Wbb -> MFMA B-frag layout (bf16) ----------------
// Wbbf[((kstep*8+nt)*64+lane)*8+j] = Wbb[(kstep*32+(lane>>4)*8+j)*128 + nt*16+(lane&15)]
__global__ void prep_wbbf(const float* __restrict__ Wbb, unsigned short* __restrict__ Wbbf) {
    int i = blockIdx.x * blockDim.x + threadIdx.x;   // 1605632
    int j = i & 7, lane = (i >> 3) & 63, nt = (i >> 9) & 7, kstep = i >> 12;
    int f = kstep * 32 + (lane >> 4) * 8 + j;
    int col = nt * 16 + (lane & 15);
    Wbbf[i] = f2bf(Wbb[(size_t)f * 128 + col]);
}

// ---------------- conv1 as implicit GEMM, bf16 MFMA ----------------
// Per block: 1 image. M=900 (57 tiles of 16, clamp/mask), N=32 (2 ntiles),
// K=48 -> 2 ksteps of 32 (kstep1 upper half zero). Same (lane,j)->k labeling
// on A and B as conv2 (validated), so the contraction is exact conv.
// x staged to LDS as bf16 [c][y][x], row pitch 33 dwords (bank-decorrelates
// the 4 g-groups), plane pitch 2046 dwords.
__global__ __launch_bounds__(256) void conv1_mfma(const float* __restrict__ x,
                                                  const float* __restrict__ b1,
                                                  const unsigned short* __restrict__ w1f,
                                                  unsigned short* __restrict__ h1b) {
    __shared__ unsigned int xs32[3 * 2046];        // 24.6 KB
    int img = blockIdx.x;
    int tid = threadIdx.x;
    const float* xg = x + (size_t)img * 11532;
    // stage: fp32 -> bf16 pairs; dword d covers x[c, y, 2*xd .. 2*xd+1]
    for (int d = tid; d < 5766; d += 256) {
        int c = d / 1922, r = d - c * 1922;
        int y = r / 31, xd = r - y * 31;
        const float* s = xg + c * 3844 + y * 62 + xd * 2;
        unsigned int lo = f2bf(s[0]), hi = f2bf(s[1]);
        xs32[c * 2046 + y * 33 + xd] = lo | (hi << 16);
    }
    __syncthreads();

    int lane = tid & 63, wid = tid >> 6;
    int rowl = lane & 15, g = lane >> 4;

    // B-fragments (held in VGPRs for the whole kernel)
    short8 bfr[2][2];
    #pragma unroll
    for (int ks = 0; ks < 2; ++ks)
        #pragma unroll
        for (int nt = 0; nt < 2; ++nt)
            bfr[ks][nt] = *(const short8*)(w1f + (((ks * 2 + nt) * 64 + lane) << 3));
    float bias0 = b1[rowl], bias1 = b1[16 + rowl];

    for (int i = 0; i < 15; ++i) {
        int mtile = wid + 4 * i;
        if (mtile >= 57) break;
        int m = mtile * 16 + rowl; if (m > 899) m = 899;
        int oy = m / 30, ox = m - oy * 30;
        int dof = (2 * oy + g) * 33 + ox;          // dword offset in plane
        union { unsigned int u[4]; short8 s; } af0, af1;
        af0.u[0] = xs32[dof];          af0.u[1] = xs32[dof + 1];
        af0.u[2] = xs32[2046 + dof];   af0.u[3] = xs32[2046 + dof + 1];
        af1.u[0] = xs32[4092 + dof];   af1.u[1] = xs32[4092 + dof + 1];
        af1.u[2] = 0;                  af1.u[3] = 0;
        f32x4 acc0 = (f32x4){0.f, 0.f, 0.f, 0.f};
        f32x4 acc1 = (f32x4){0.f, 0.f, 0.f, 0.f};
        acc0 = __builtin_amdgcn_mfma_f32_16x16x32_bf16(af0.s, bfr[0][0], acc0, 0, 0, 0);
        acc0 = __builtin_amdgcn_mfma_f32_16x16x32_bf16(af1.s, bfr[1][0], acc0, 0, 0, 0);
        acc1 = __builtin_amdgcn_mfma_f32_16x16x32_bf16(af0.s, bfr[0][1], acc1, 0, 0, 0);
        acc1 = __builtin_amdgcn_mfma_f32_16x16x32_bf16(af1.s, bfr[1][1], acc1, 0, 0, 0);
        // epilogue: bias + relu + bf16 -> h1b[img][oc*900 + sp]
        int sp0 = mtile * 16 + g * 4;
        #pragma unroll
        for (int nt = 0; nt < 2; ++nt) {
            f32x4 a = nt ? acc1 : acc0;
            int oc = nt * 16 + rowl;
            float bias = nt ? bias1 : bias0;
            unsigned short pk[4];
            #pragma unroll
            for (int r = 0; r < 4; ++r) pk[r] = f2bf(fmaxf(a[r] + bias, 0.f));
            unsigned short* dstp = h1b + (size_t)img * 28800 + oc * 900 + sp0;
            if (sp0 + 3 < 900) {
                *(uint2*)dstp = *(uint2*)pk;       // (oc*900+sp0)%4==0 -> 8B aligned
            } else {
                #pragma unroll
                for (int r = 0; r < 4; ++r) if (sp0 + r < 900) dstp[r] = pk[r];
            }
        }
    }
}

// ---------------- conv2 as implicit GEMM, bf16 MFMA ----------------
__global__ __launch_bounds__(256) void conv2_mfma(const unsigned short* __restrict__ h1b,
                                                  const float* __restrict__ b2,
                                                  const unsigned short* __restrict__ w2f,
                                                  unsigned short* __restrict__ featb) {
    __shared__ unsigned short h1s[32 * 30 * 32];   // [ic][y][x pad 32] = 60 KB
    int img = blockIdx.x;
    int tid = threadIdx.x;
    {
        const unsigned int* src = (const unsigned int*)(h1b + (size_t)img * 28800);
        unsigned int* dst = (unsigned int*)h1s;
        for (int d = tid; d < 14400; d += 256) {
            int ic = d / 450, r = d - ic * 450;
            int y = r / 15, x2 = r - y * 15;
            dst[(ic * 30 + y) * 16 + x2] = src[d];
        }
    }
    __syncthreads();
    int lane = tid & 63, wid = tid >> 6;
    int rowl = lane & 15, g = lane >> 4;

    f32x4 acc[4][4];
    #pragma unroll
    for (int i = 0; i < 4; ++i)
        #pragma unroll
        for (int nt = 0; nt < 4; ++nt) acc[i][nt] = (f32x4){0.f, 0.f, 0.f, 0.f};

    int dofs[4];
    #pragma unroll
    for (int i = 0; i < 4; ++i) {
        int mtile = wid + 4 * i;
        int m = mtile * 16 + rowl; if (m > 195) m = 195;
        int oy = m / 14, ox = m - oy * 14;
        int y = 2 * oy + g, x0 = 2 * ox;
        dofs[i] = y * 16 + (x0 >> 1);
    }
    const unsigned int* lds32 = (const unsigned int*)h1s;

    #pragma unroll 4
    for (int kstep = 0; kstep < 16; ++kstep) {
        short8 bfr[4];
        #pragma unroll
        for (int nt = 0; nt < 4; ++nt)
            bfr[nt] = *(const short8*)(w2f + (((nt * 16 + kstep) * 64 + lane) << 3));
        int icb = kstep * 960;
        #pragma unroll
        for (int i = 0; i < 4; ++i) {
            int mtile = wid + 4 * i;
            if (mtile < 13) {
                int dof = icb + dofs[i];
                union { unsigned int u[4]; short8 s; } af;
                af.u[0] = lds32[dof];
                af.u[1] = lds32[dof + 1];
                af.u[2] = lds32[dof + 480];
                af.u[3] = lds32[dof + 481];
                #pragma unroll
                for (int nt = 0; nt < 4; ++nt)
                    acc[i][nt] = __builtin_amdgcn_mfma_f32_16x16x32_bf16(af.s, bfr[nt], acc[i][nt], 0, 0, 0);
            }
        }
    }
    #pragma unroll
    for (int i = 0; i < 4; ++i) {
        int mtile = wid + 4 * i;
        if (mtile >= 13) continue;
        int sp0 = mtile * 16 + g * 4;
        #pragma unroll
        for (int nt = 0; nt < 4; ++nt) {
            int oc = nt * 16 + rowl;
            float bias = b2[oc];
            unsigned short pk[4];
            #pragma unroll
            for (int r = 0; r < 4; ++r)
                pk[r] = f2bf(fmaxf(acc[i][nt][r] + bias, 0.f));
            unsigned short* dstp = featb + (size_t)img * 12544 + oc * 196 + sp0;
            if (sp0 + 3 < 196) {
                *(uint2*)dstp = *(uint2*)pk;
            } else {
                #pragma unroll
                for (int r = 0; r < 4; ++r) if (sp0 + r < 196) dstp[r] = pk[r];
            }
        }
    }
}

// ---------------- u = feat @ W_in : bf16 MFMA, split-K=28 ----------------
__global__ __launch_bounds__(256) void gemm_u_mfma(const unsigned short* __restrict__ featb,
                                                   const unsigned short* __restrict__ Wbbf,
                                                   float* __restrict__ part) {
    int tid = threadIdx.x, lane = tid & 63, wid = tid >> 6;
    int rowl = lane & 15, g = lane >> 4;
    int m0 = blockIdx.x * 64 + wid * 16;
    int ks0 = blockIdx.y * 14;
    f32x4 acc[8];
    #pragma unroll
    for (int nt = 0; nt < 8; ++nt) acc[nt] = (f32x4){0.f, 0.f, 0.f, 0.f};
    const unsigned short* arow = featb + (size_t)(m0 + rowl) * FEATN + g * 8;
    #pragma unroll 2
    for (int kk = 0; kk < 14; ++kk) {
        int kstep = ks0 + kk;
        short8 afr = *(const short8*)(arow + kstep * 32);
        #pragma unroll
        for (int nt = 0; nt < 8; ++nt) {
            short8 bfr = *(const short8*)(Wbbf + ((((size_t)kstep * 8 + nt) * 64 + lane) << 3));
            acc[nt] = __builtin_amdgcn_mfma_f32_16x16x32_bf16(afr, bfr, acc[nt], 0, 0, 0);
        }
    }
    float* pg = part + (size_t)blockIdx.y * 131072;
    #pragma unroll
    for (int nt = 0; nt < 8; ++nt)
        #pragma unroll
        for (int r = 0; r < 4; ++r)
            pg[(m0 + g * 4 + r) * 128 + nt * 16 + rowl] = acc[nt][r];
}

__global__ void reduce_u(const float* __restrict__ part, const float* __restrict__ bbb,
                         float* __restrict__ u) {
    int i = blockIdx.x * 256 + threadIdx.x;   // 131072 total
    float s = bbb[i & 127];
    #pragma unroll
    for (int ks = 0; ks < 28; ++ks) s += part[(size_t)ks * 131072 + i];
    u[i] = s;
}

// ---------------- liquid RNN scan ----------------
__global__ __launch_bounds__(256, 1) void rnn_kernel(const float* __restrict__ u,
                                                  const float* __restrict__ Wbb,
                                                  const float* __restrict__ Wff1, const float* __restrict__ bff1,
                                                  const float* __restrict__ Wff2, const float* __restrict__ bff2,
                                                  const float* __restrict__ Wta,  const float* __restrict__ bta,
                                                  const float* __restrict__ Wtb,  const float* __restrict__ btb,
                                                  float* __restrict__ hid_out) {
    __shared__ float u_s[64 * 128];
    __shared__ float hid_s[64];
    __shared__ float zs[128];
    __shared__ float fsts[4][64];
    int b = blockIdx.x;
    int tid = threadIdx.x;
    {
        const float4* ug = (const float4*)(u + (size_t)b * 8192);
        float4* us4 = (float4*)u_s;
        for (int idx = tid; idx < 2048; idx += 256) us4[idx] = ug[idx];
    }
    const float* Wh = Wbb + (size_t)FEATN * 128;
    float wh[64];
    if (tid < 128) {
        #pragma unroll
        for (int j = 0; j < 64; ++j) wh[j] = Wh[j * 128 + tid];
    }
    int grp = tid >> 6, i = tid & 63;
    const float* Wg = (grp == 0) ? Wff1 : (grp == 1) ? Wff2 : (grp == 2) ? Wta : Wtb;
    float wc[128];
    #pragma unroll
    for (int k = 0; k < 128; ++k) wc[k] = Wg[k * 64 + i];
    float bf1 = 0.f, bf2 = 0.f, bts = 0.f;
    if (tid < 64) {
        bf1 = bff1[tid]; bf2 = bff2[tid]; bts = bta[tid] + btb[tid];
        hid_s[tid] = 0.f;
    }
    __syncthreads();
    for (int t = 0; t < 64; ++t) {
        if (tid < 128) {
            float a0 = u_s[t * 128 + tid], a1 = 0.f, a2 = 0.f, a3 = 0.f;
            #pragma unroll
            for (int j = 0; j < 64; j += 4) {
                a0 += hid_s[j    ] * wh[j    ];
                a1 += hid_s[j + 1] * wh[j + 1];
                a2 += hid_s[j + 2] * wh[j + 2];
                a3 += hid_s[j + 3] * wh[j + 3];
            }
            float a = (a0 + a1) + (a2 + a3);
            zs[tid] = 1.7159f * fast_tanh(0.666f * a);
        }
        __syncthreads();
        {
            float s0 = 0.f, s1 = 0.f, s2 = 0.f, s3 = 0.f;
            #pragma unroll
            for (int k = 0; k < 128; k += 4) {
                s0 += zs[k    ] * wc[k    ];
                s1 += zs[k + 1] * wc[k + 1];
                s2 += zs[k + 2] * wc[k + 2];
                s3 += zs[k + 3] * wc[k + 3];
            }
            fsts[grp][i] = (s0 + s1) + (s2 + s3);
        }
        __syncthreads();
        if (tid < 64) {
            float ff1 = fast_tanh(fsts[0][tid] + bf1);
            float ff2 = fast_tanh(fsts[1][tid] + bf2);
            float tt  = fast_sigmoid(fsts[2][tid] + fsts[3][tid] + bts);
            hid_s[tid] = ff1 * (1.f - tt) + tt * ff2;
        }
        __syncthreads();
    }
    if (tid < 64) hid_out[b * 64 + tid] = hid_s[tid];
}

// ---------------- head ----------------
__global__ void head_kernel(const float* __restrict__ hid, const float* __restrict__ Wout,
                            const float* __restrict__ bout, float* __restrict__ out) {
    int tid = threadIdx.x;           // 128 = 16*8
    int b = tid >> 3, a = tid & 7;
    float s = bout[a];
    #pragma unroll
    for (int j = 0; j < 64; ++j) s += hid[b * 64 + j] * Wout[j * 8 + a];
    out[tid] = s;
}

extern "C" void kernel_launch(void* const* d_in, const int* in_sizes, int n_in,
                              void* d_out, int out_size, void* d_ws, size_t ws_size,
                              hipStream_t stream) {
    const float* x    = (const float*)d_in[0];
    const float* w1   = (const float*)d_in[1];
    const float* b1   = (const float*)d_in[2];
    const float* w2   = (const float*)d_in[3];
    const float* b2   = (const float*)d_in[4];
    const float* Wbb  = (const float*)d_in[5];
    const float* bbb  = (const float*)d_in[6];
    const float* Wff1 = (const float*)d_in[7];
    const float* bff1 = (const float*)d_in[8];
    const float* Wff2 = (const float*)d_in[9];
    const float* bff2 = (const float*)d_in[10];
    const float* Wta  = (const float*)d_in[11];
    const float* bta  = (const float*)d_in[12];
    const float* Wtb  = (const float*)d_in[13];
    const float* btb  = (const float*)d_in[14];
    const float* Wout = (const float*)d_in[15];
    const float* bout = (const float*)d_in[16];

    if (ws_size < (size_t)WS_BYTES) return;

    char* wsb = (char*)d_ws;
    unsigned short* w1f   = (unsigned short*)(wsb + OFF_W1F);
    unsigned short* w2f   = (unsigned short*)(wsb + OFF_W2F);
    unsigned short* wbbf  = (unsigned short*)(wsb + OFF_WBBF);
    unsigned short* h1b   = (unsigned short*)(wsb + OFF_H1B);
    unsigned short* featb = (unsigned short*)(wsb + OFF_FEATB);
    float*          u     = (float*)(wsb + OFF_U);
    float*          part  = (float*)(wsb + OFF_PART);
    float*          hid   = (float*)(wsb + OFF_HID);

    prep_w1f <<<8, 256, 0, stream>>>(w1, w1f);
    prep_w2f <<<128, 256, 0, stream>>>(w2, w2f);
    prep_wbbf<<<6272, 256, 0, stream>>>(Wbb, wbbf);
    conv1_mfma<<<1024, 256, 0, stream>>>(x, b1, w1f, h1b);
    conv2_mfma<<<1024, 256, 0, stream>>>(h1b, b2, w2f, featb);
    gemm_u_mfma<<<dim3(16, 28), 256, 0, stream>>>(featb, wbbf, part);
    reduce_u<<<512, 256, 0, stream>>>(part, bbb, u);
    rnn_kernel<<<16, 256, 0, stream>>>(u, Wbb, Wff1, bff1, Wff2, bff2, Wta, bta, Wtb, btb, hid);
    head_kernel<<<1, 128, 0, stream>>>(hid, Wout, bout, (float*)d_out);
}

// Round 6
// 197.718 us; speedup vs baseline: 4.2799x; 1.0060x over previous
//
#include <hip/hip_runtime.h>
#include <hip/hip_bf16.h>
#include <math.h>

#define FEATN 12544
#define NIMG 1024

typedef __attribute__((ext_vector_type(8))) short short8;
typedef __attribute__((ext_vector_type(4))) float f32x4;

// ---- ws byte offsets (all sizes in BYTES; bf16 regions are 2 B/elem) ----
#define OFF_W1F   0            //  2048 bf16  =     4096 B   conv1 B-frag table
#define OFF_W2F   6144         //  32768 bf16 =    65536 B   conv2 B-frag table
#define OFF_WBBF  71680        //  1605632 bf16 = 3211264 B  gemm_u B-frag table
#define OFF_H1B   3282944      //  1024*28800 bf16 = 58982400 B
#define OFF_FEATB 62265344     //  1024*12544 bf16 = 25690112 B
#define OFF_U     87955456     //  131072 f32 = 524288 B
#define OFF_PART  88479744     //  28*131072 f32 = 14680064 B
#define OFF_HID   103159808    //  1024 f32 = 4096 B
#define WS_BYTES  103163904

__device__ __forceinline__ unsigned short f2bf(float v) {
    union { float f; unsigned int u; } c; c.f = v;
    unsigned int r = c.u + 0x7FFFu + ((c.u >> 16) & 1u);   // RNE
    return (unsigned short)(r >> 16);
}

__device__ __forceinline__ float fast_tanh(float x) {
    x = fminf(fmaxf(x, -15.f), 15.f);
    float e = __expf(2.f * x);
    return (e - 1.f) * __builtin_amdgcn_rcpf(e + 1.f);
}
__device__ __forceinline__ float fast_sigmoid(float x) {
    x = fminf(fmaxf(x, -30.f), 30.f);
    return __builtin_amdgcn_rcpf(1.f + __expf(-x));
}

// ---------------- prep: conv1 weights -> MFMA B-frag layout (bf16) ----------------
__global__ void prep_w1f(const float* __restrict__ w1, unsigned short* __restrict__ w1f) {
    int i = blockIdx.x * blockDim.x + threadIdx.x;   // 2048
    if (i >= 2048) return;
    int j = i & 7, lane = (i >> 3) & 63, nt = (i >> 9) & 1, kstep = (i >> 10) & 1;
    int oc = nt * 16 + (lane & 15);
    int ky = (lane >> 4) & 3, kx = j & 3;
    float v;
    if (kstep == 0) {
        int ic = j >> 2;
        v = w1[oc * 48 + ic * 16 + ky * 4 + kx];
    } else {
        v = (j >> 2) == 0 ? w1[oc * 48 + 32 + ky * 4 + kx] : 0.f;
    }
    w1f[i] = f2bf(v);
}

// ---------------- prep: conv2 weights -> MFMA B-frag layout (bf16) ----------------
__global__ void prep_w2f(const float* __restrict__ w2, unsigned short* __restrict__ w2f) {
    int i = blockIdx.x * blockDim.x + threadIdx.x;   // 32768
    int j = i & 7, lane = (i >> 3) & 63, kstep = (i >> 9) & 15, nt = i >> 13;
    int oc = nt * 16 + (lane & 15);
    int ic = 2 * kstep + (j >> 2);
    int ky = lane >> 4, kx = j & 3;
    w2f[i] = f2bf(w2[oc * 512 + ic * 16 + ky * 4 + kx]);
}

// ---------------- prep: Wbb -> MFMA B-frag layout (bf16) ----------------
__global__ void prep_wbbf(const float* __restrict__ Wbb, unsigned short* __restrict__ Wbbf) {
    int i = blockIdx.x * blockDim.x + threadIdx.x;   // 1605632
    int j = i & 7, lane = (i >> 3) & 63, nt = (i >> 9) & 7, kstep = i >> 12;
    int f = kstep * 32 + (lane >> 4) * 8 + j;
    int col = nt * 16 + (lane & 15);
    Wbbf[i] = f2bf(Wbb[(size_t)f * 128 + col]);
}

// ---------------- conv1 as implicit GEMM, bf16 MFMA ----------------
__global__ __launch_bounds__(256) void conv1_mfma(const float* __restrict__ x,
                                                  const float* __restrict__ b1,
                                                  const unsigned short* __restrict__ w1f,
                                                  unsigned short* __restrict__ h1b) {
    __shared__ unsigned int xs32[3 * 2046];        // 24.6 KB
    int img = blockIdx.x;
    int tid = threadIdx.x;
    const float* xg = x + (size_t)img * 11532;
    for (int d = tid; d < 5766; d += 256) {
        int c = d / 1922, r = d - c * 1922;
        int y = r / 31, xd = r - y * 31;
        const float* s = xg + c * 3844 + y * 62 + xd * 2;
        unsigned int lo = f2bf(s[0]), hi = f2bf(s[1]);
        xs32[c * 2046 + y * 33 + xd] = lo | (hi << 16);
    }
    __syncthreads();

    int lane = tid & 63, wid = tid >> 6;
    int rowl = lane & 15, g = lane >> 4;

    short8 bfr[2][2];
    #pragma unroll
    for (int ks = 0; ks < 2; ++ks)
        #pragma unroll
        for (int nt = 0; nt < 2; ++nt)
            bfr[ks][nt] = *(const short8*)(w1f + (((ks * 2 + nt) * 64 + lane) << 3));
    float bias0 = b1[rowl], bias1 = b1[16 + rowl];

    for (int i = 0; i < 15; ++i) {
        int mtile = wid + 4 * i;
        if (mtile >= 57) break;
        int m = mtile * 16 + rowl; if (m > 899) m = 899;
        int oy = m / 30, ox = m - oy * 30;
        int dof = (2 * oy + g) * 33 + ox;
        union { unsigned int u[4]; short8 s; } af0, af1;
        af0.u[0] = xs32[dof];          af0.u[1] = xs32[dof + 1];
        af0.u[2] = xs32[2046 + dof];   af0.u[3] = xs32[2046 + dof + 1];
        af1.u[0] = xs32[4092 + dof];   af1.u[1] = xs32[4092 + dof + 1];
        af1.u[2] = 0;                  af1.u[3] = 0;
        f32x4 acc0 = (f32x4){0.f, 0.f, 0.f, 0.f};
        f32x4 acc1 = (f32x4){0.f, 0.f, 0.f, 0.f};
        acc0 = __builtin_amdgcn_mfma_f32_16x16x32_bf16(af0.s, bfr[0][0], acc0, 0, 0, 0);
        acc0 = __builtin_amdgcn_mfma_f32_16x16x32_bf16(af1.s, bfr[1][0], acc0, 0, 0, 0);
        acc1 = __builtin_amdgcn_mfma_f32_16x16x32_bf16(af0.s, bfr[0][1], acc1, 0, 0, 0);
        acc1 = __builtin_amdgcn_mfma_f32_16x16x32_bf16(af1.s, bfr[1][1], acc1, 0, 0, 0);
        int sp0 = mtile * 16 + g * 4;
        #pragma unroll
        for (int nt = 0; nt < 2; ++nt) {
            f32x4 a = nt ? acc1 : acc0;
            int oc = nt * 16 + rowl;
            float bias = nt ? bias1 : bias0;
            unsigned short pk[4];
            #pragma unroll
            for (int r = 0; r < 4; ++r) pk[r] = f2bf(fmaxf(a[r] + bias, 0.f));
            unsigned short* dstp = h1b + (size_t)img * 28800 + oc * 900 + sp0;
            if (sp0 + 3 < 900) {
                *(uint2*)dstp = *(uint2*)pk;
            } else {
                #pragma unroll
                for (int r = 0; r < 4; ++r) if (sp0 + r < 900) dstp[r] = pk[r];
            }
        }
    }
}

// ---------------- conv2 as implicit GEMM, bf16 MFMA ----------------
__global__ __launch_bounds__(256) void conv2_mfma(const unsigned short* __restrict__ h1b,
                                                  const float* __restrict__ b2,
                                                  const unsigned short* __restrict__ w2f,
                                                  unsigned short* __restrict__ featb) {
    __shared__ unsigned short h1s[32 * 30 * 32];   // [ic][y][x pad 32] = 60 KB
    int img = blockIdx.x;
    int tid = threadIdx.x;
    {
        const unsigned int* src = (const unsigned int*)(h1b + (size_t)img * 28800);
        unsigned int* dst = (unsigned int*)h1s;
        for (int d = tid; d < 14400; d += 256) {
            int ic = d / 450, r = d - ic * 450;
            int y = r / 15, x2 = r - y * 15;
            dst[(ic * 30 + y) * 16 + x2] = src[d];
        }
    }
    __syncthreads();
    int lane = tid & 63, wid = tid >> 6;
    int rowl = lane & 15, g = lane >> 4;

    f32x4 acc[4][4];
    #pragma unroll
    for (int i = 0; i < 4; ++i)
        #pragma unroll
        for (int nt = 0; nt < 4; ++nt) acc[i][nt] = (f32x4){0.f, 0.f, 0.f, 0.f};

    int dofs[4];
    #pragma unroll
    for (int i = 0; i < 4; ++i) {
        int mtile = wid + 4 * i;
        int m = mtile * 16 + rowl; if (m > 195) m = 195;
        int oy = m / 14, ox = m - oy * 14;
        int y = 2 * oy + g, x0 = 2 * ox;
        dofs[i] = y * 16 + (x0 >> 1);
    }
    const unsigned int* lds32 = (const unsigned int*)h1s;

    #pragma unroll 4
    for (int kstep = 0; kstep < 16; ++kstep) {
        short8 bfr[4];
        #pragma unroll
        for (int nt = 0; nt < 4; ++nt)
            bfr[nt] = *(const short8*)(w2f + (((nt * 16 + kstep) * 64 + lane) << 3));
        int icb = kstep * 960;
        #pragma unroll
        for (int i = 0; i < 4; ++i) {
            int mtile = wid + 4 * i;
            if (mtile < 13) {
                int dof = icb + dofs[i];
                union { unsigned int u[4]; short8 s; } af;
                af.u[0] = lds32[dof];
                af.u[1] = lds32[dof + 1];
                af.u[2] = lds32[dof + 480];
                af.u[3] = lds32[dof + 481];
                #pragma unroll
                for (int nt = 0; nt < 4; ++nt)
                    acc[i][nt] = __builtin_amdgcn_mfma_f32_16x16x32_bf16(af.s, bfr[nt], acc[i][nt], 0, 0, 0);
            }
        }
    }
    #pragma unroll
    for (int i = 0; i < 4; ++i) {
        int mtile = wid + 4 * i;
        if (mtile >= 13) continue;
        int sp0 = mtile * 16 + g * 4;
        #pragma unroll
        for (int nt = 0; nt < 4; ++nt) {
            int oc = nt * 16 + rowl;
            float bias = b2[oc];
            unsigned short pk[4];
            #pragma unroll
            for (int r = 0; r < 4; ++r)
                pk[r] = f2bf(fmaxf(acc[i][nt][r] + bias, 0.f));
            unsigned short* dstp = featb + (size_t)img * 12544 + oc * 196 + sp0;
            if (sp0 + 3 < 196) {
                *(uint2*)dstp = *(uint2*)pk;
            } else {
                #pragma unroll
                for (int r = 0; r < 4; ++r) if (sp0 + r < 196) dstp[r] = pk[r];
            }
        }
    }
}

// ---------------- u = feat @ W_in : bf16 MFMA, split-K=28 ----------------
__global__ __launch_bounds__(256) void gemm_u_mfma(const unsigned short* __restrict__ featb,
                                                   const unsigned short* __restrict__ Wbbf,
                                                   float* __restrict__ part) {
    int tid = threadIdx.x, lane = tid & 63, wid = tid >> 6;
    int rowl = lane & 15, g = lane >> 4;
    int m0 = blockIdx.x * 64 + wid * 16;
    int ks0 = blockIdx.y * 14;
    f32x4 acc[8];
    #pragma unroll
    for (int nt = 0; nt < 8; ++nt) acc[nt] = (f32x4){0.f, 0.f, 0.f, 0.f};
    const unsigned short* arow = featb + (size_t)(m0 + rowl) * FEATN + g * 8;
    #pragma unroll 2
    for (int kk = 0; kk < 14; ++kk) {
        int kstep = ks0 + kk;
        short8 afr = *(const short8*)(arow + kstep * 32);
        #pragma unroll
        for (int nt = 0; nt < 8; ++nt) {
            short8 bfr = *(const short8*)(Wbbf + ((((size_t)kstep * 8 + nt) * 64 + lane) << 3));
            acc[nt] = __builtin_amdgcn_mfma_f32_16x16x32_bf16(afr, bfr, acc[nt], 0, 0, 0);
        }
    }
    float* pg = part + (size_t)blockIdx.y * 131072;
    #pragma unroll
    for (int nt = 0; nt < 8; ++nt)
        #pragma unroll
        for (int r = 0; r < 4; ++r)
            pg[(m0 + g * 4 + r) * 128 + nt * 16 + rowl] = acc[nt][r];
}

__global__ void reduce_u(const float* __restrict__ part, const float* __restrict__ bbb,
                         float* __restrict__ u) {
    int i = blockIdx.x * 256 + threadIdx.x;   // 131072 total
    float s = bbb[i & 127];
    #pragma unroll
    for (int ks = 0; ks < 28; ++ks) s += part[(size_t)ks * 131072 + i];
    u[i] = s;
}

// ---------------- liquid RNN scan: float4 LDS traffic, register weights ----------------
__global__ __launch_bounds__(256, 1) void rnn_kernel(const float* __restrict__ u,
                                                  const float* __restrict__ Wbb,
                                                  const float* __restrict__ Wff1, const float* __restrict__ bff1,
                                                  const float* __restrict__ Wff2, const float* __restrict__ bff2,
                                                  const float* __restrict__ Wta,  const float* __restrict__ bta,
                                                  const float* __restrict__ Wtb,  const float* __restrict__ btb,
                                                  float* __restrict__ hid_out) {
    __shared__ float u_s[64 * 128];
    __shared__ float hid_s[64];
    __shared__ float zs[128];
    __shared__ float fsts[4][64];
    int b = blockIdx.x;
    int tid = threadIdx.x;
    {
        const float4* ug = (const float4*)(u + (size_t)b * 8192);
        float4* us4 = (float4*)u_s;
        for (int idx = tid; idx < 2048; idx += 256) us4[idx] = ug[idx];
    }
    const float* Wh = Wbb + (size_t)FEATN * 128;
    float wh[64];
    if (tid < 128) {
        #pragma unroll
        for (int j = 0; j < 64; ++j) wh[j] = Wh[j * 128 + tid];   // coalesced per j
    }
    int grp = tid >> 6, i = tid & 63;
    const float* Wg = (grp == 0) ? Wff1 : (grp == 1) ? Wff2 : (grp == 2) ? Wta : Wtb;
    float wc[128];
    #pragma unroll
    for (int k = 0; k < 128; ++k) wc[k] = Wg[k * 64 + i];         // coalesced per k
    float bf1 = 0.f, bf2 = 0.f, bts = 0.f;
    if (tid < 64) {
        bf1 = bff1[tid]; bf2 = bff2[tid]; bts = bta[tid] + btb[tid];
        hid_s[tid] = 0.f;
    }
    __syncthreads();

    const float4* h4 = (const float4*)hid_s;
    const float4* z4 = (const float4*)zs;

    for (int t = 0; t < 64; ++t) {
        if (tid < 128) {
            // z = lecun_tanh(u_t + hid @ Wh): 16 x ds_read_b128 (broadcast)
            float a0 = u_s[t * 128 + tid], a1 = 0.f, a2 = 0.f, a3 = 0.f;
            #pragma unroll
            for (int q = 0; q < 16; ++q) {
                float4 h = h4[q];
                a0 += h.x * wh[4 * q    ];
                a1 += h.y * wh[4 * q + 1];
                a2 += h.z * wh[4 * q + 2];
                a3 += h.w * wh[4 * q + 3];
            }
            float a = (a0 + a1) + (a2 + a3);
            zs[tid] = 1.7159f * fast_tanh(0.666f * a);
        }
        __syncthreads();
        {
            // fsts[grp] = z @ Wg: 32 x ds_read_b128 (broadcast)
            float s0 = 0.f, s1 = 0.f, s2 = 0.f, s3 = 0.f;
            #pragma unroll
            for (int q = 0; q < 32; ++q) {
                float4 z = z4[q];
                s0 += z.x * wc[4 * q    ];
                s1 += z.y * wc[4 * q + 1];
                s2 += z.z * wc[4 * q + 2];
                s3 += z.w * wc[4 * q + 3];
            }
            fsts[grp][i] = (s0 + s1) + (s2 + s3);
        }
        __syncthreads();
        if (tid < 64) {
            float ff1 = fast_tanh(fsts[0][tid] + bf1);
            float ff2 = fast_tanh(fsts[1][tid] + bf2);
            float tt  = fast_sigmoid(fsts[2][tid] + fsts[3][tid] + bts);
            hid_s[tid] = ff1 * (1.f - tt) + tt * ff2;
        }
        __syncthreads();
    }
    if (tid < 64) hid_out[b * 64 + tid] = hid_s[tid];
}

// ---------------- head ----------------
__global__ void head_kernel(const float* __restrict__ hid, const float* __restrict__ Wout,
                            const float* __restrict__ bout, float* __restrict__ out) {
    int tid = threadIdx.x;           // 128 = 16*8
    int b = tid >> 3, a = tid & 7;
    float s = bout[a];
    #pragma unroll
    for (int j = 0; j < 64; ++j) s += hid[b * 64 + j] * Wout[j * 8 + a];
    out[tid] = s;
}

extern "C" void kernel_launch(void* const* d_in, const int* in_sizes, int n_in,
                              void* d_out, int out_size, void* d_ws, size_t ws_size,
                              hipStream_t stream) {
    const float* x    = (const float*)d_in[0];
    const float* w1   = (const float*)d_in[1];
    const float* b1   = (const float*)d_in[2];
    const float* w2   = (const float*)d_in[3];
    const float* b2   = (const float*)d_in[4];
    const float* Wbb  = (const float*)d_in[5];
    const float* bbb  = (const float*)d_in[6];
    const float* Wff1 = (const float*)d_in[7];
    const float* bff1 = (const float*)d_in[8];
    const float* Wff2 = (const float*)d_in[9];
    const float* bff2 = (const float*)d_in[10];
    const float* Wta  = (const float*)d_in[11];
    const float* bta  = (const float*)d_in[12];
    const float* Wtb  = (const float*)d_in[13];
    const float* btb  = (const float*)d_in[14];
    const float* Wout = (const float*)d_in[15];
    const float* bout = (const float*)d_in[16];

    if (ws_size < (size_t)WS_BYTES) return;

    char* wsb = (char*)d_ws;
    unsigned short* w1f   = (unsigned short*)(wsb + OFF_W1F);
    unsigned short* w2f   = (unsigned short*)(wsb + OFF_W2F);
    unsigned short* wbbf  = (unsigned short*)(wsb + OFF_WBBF);
    unsigned short* h1b   = (unsigned short*)(wsb + OFF_H1B);
    unsigned short* featb = (unsigned short*)(wsb + OFF_FEATB);
    float*          u     = (float*)(wsb + OFF_U);
    float*          part  = (float*)(wsb + OFF_PART);
    float*          hid   = (float*)(wsb + OFF_HID);

    prep_w1f <<<8, 256, 0, stream>>>(w1, w1f);
    prep_w2f <<<128, 256, 0, stream>>>(w2, w2f);
    prep_wbbf<<<6272, 256, 0, stream>>>(Wbb, wbbf);
    conv1_mfma<<<1024, 256, 0, stream>>>(x, b1, w1f, h1b);
    conv2_mfma<<<1024, 256, 0, stream>>>(h1b, b2, w2f, featb);
    gemm_u_mfma<<<dim3(16, 28), 256, 0, stream>>>(featb, wbbf, part);
    reduce_u<<<512, 256, 0, stream>>>(part, bbb, u);
    rnn_kernel<<<16, 256, 0, stream>>>(u, Wbb, Wff1, bff1, Wff2, bff2, Wta, bta, Wtb, btb, hid);
    head_kernel<<<1, 128, 0, stream>>>(hid, Wout, bout, (float*)d_out);
}

// Round 7
// 184.272 us; speedup vs baseline: 4.5922x; 1.0730x over previous
//
#include <hip/hip_runtime.h>
#include <hip/hip_bf16.h>
#include <math.h>

#define FEATN 12544
#define NIMG 1024

typedef __attribute__((ext_vector_type(8))) short short8;
typedef __attribute__((ext_vector_type(4))) float f32x4;

// ---- ws byte offsets (all sizes in BYTES; bf16 regions are 2 B/elem) ----
#define OFF_W1F   0            //  2048 bf16  =     4096 B   conv1 B-frag table
#define OFF_W2F   6144         //  32768 bf16 =    65536 B   conv2 B-frag table
#define OFF_WBBF  71680        //  1605632 bf16 = 3211264 B  gemm_u B-frag table
#define OFF_H1B   3282944      //  1024*28800 bf16 = 58982400 B
#define OFF_FEATB 62265344     //  1024*12544 bf16 = 25690112 B
#define OFF_U     87955456     //  131072 f32 = 524288 B   (layout [t][b][128])
#define OFF_PART  88479744     //  28*131072 f32 = 14680064 B
#define OFF_HID   103159808    //  1024 f32 = 4096 B
#define OFF_WHF   103163904    //  8192 bf16 = 16384 B   rnn Wh B-frag table
#define OFF_WGF   103180288    //  32768 bf16 = 65536 B  rnn [ff1|ff2|ta|tb] B-frag table
#define WS_BYTES  103245824

__device__ __forceinline__ unsigned short f2bf(float v) {
    union { float f; unsigned int u; } c; c.f = v;
    unsigned int r = c.u + 0x7FFFu + ((c.u >> 16) & 1u);   // RNE
    return (unsigned short)(r >> 16);
}
__device__ __forceinline__ float bf2f(unsigned short h) {
    union { unsigned int u; float f; } c; c.u = ((unsigned int)h) << 16;
    return c.f;
}

__device__ __forceinline__ float fast_tanh(float x) {
    x = fminf(fmaxf(x, -15.f), 15.f);
    float e = __expf(2.f * x);
    return (e - 1.f) * __builtin_amdgcn_rcpf(e + 1.f);
}
__device__ __forceinline__ float fast_sigmoid(float x) {
    x = fminf(fmaxf(x, -30.f), 30.f);
    return __builtin_amdgcn_rcpf(1.f + __expf(-x));
}

// ---------------- prep: conv1 weights -> MFMA B-frag layout (bf16) ----------------
__global__ void prep_w1f(const float* __restrict__ w1, unsigned short* __restrict__ w1f) {
    int i = blockIdx.x * blockDim.x + threadIdx.x;   // 2048
    if (i >= 2048) return;
    int j = i & 7, lane = (i >> 3) & 63, nt = (i >> 9) & 1, kstep = (i >> 10) & 1;
    int oc = nt * 16 + (lane & 15);
    int ky = (lane >> 4) & 3, kx = j & 3;
    float v;
    if (kstep == 0) {
        int ic = j >> 2;
        v = w1[oc * 48 + ic * 16 + ky * 4 + kx];
    } else {
        v = (j >> 2) == 0 ? w1[oc * 48 + 32 + ky * 4 + kx] : 0.f;
    }
    w1f[i] = f2bf(v);
}

// ---------------- prep: conv2 weights -> MFMA B-frag layout (bf16) ----------------
__global__ void prep_w2f(const float* __restrict__ w2, unsigned short* __restrict__ w2f) {
    int i = blockIdx.x * blockDim.x + threadIdx.x;   // 32768
    int j = i & 7, lane = (i >> 3) & 63, kstep = (i >> 9) & 15, nt = i >> 13;
    int oc = nt * 16 + (lane & 15);
    int ic = 2 * kstep + (j >> 2);
    int ky = lane >> 4, kx = j & 3;
    w2f[i] = f2bf(w2[oc * 512 + ic * 16 + ky * 4 + kx]);
}

// ---------------- prep: Wbb(feat part) -> MFMA B-frag layout (bf16) ----------------
__global__ void prep_wbbf(const float* __restrict__ Wbb, unsigned short* __restrict__ Wbbf) {
    int i = blockIdx.x * blockDim.x + threadIdx.x;   // 1605632
    int j = i & 7, lane = (i >> 3) & 63, nt = (i >> 9) & 7, kstep = i >> 12;
    int f = kstep * 32 + (lane >> 4) * 8 + j;
    int col = nt * 16 + (lane & 15);
    Wbbf[i] = f2bf(Wbb[(size_t)f * 128 + col]);
}

// ---------------- prep: Wh (= Wbb[12544:]) -> B-frags: K=64 (2 ks), N=128 (8 nt) ----------------
__global__ void prep_whf(const float* __restrict__ Wbb, unsigned short* __restrict__ whf) {
    int i = blockIdx.x * blockDim.x + threadIdx.x;   // 8192
    if (i >= 8192) return;
    int j = i & 7, lane = (i >> 3) & 63, nt = (i >> 9) & 7, kstep = (i >> 12) & 1;
    int k = kstep * 32 + ((lane >> 4) & 3) * 8 + j;          // hid dim 0..63
    int col = nt * 16 + (lane & 15);                          // z col 0..127
    whf[i] = f2bf(Wbb[(size_t)(FEATN + k) * 128 + col]);
}

// ---------------- prep: [Wff1|Wff2|Wta|Wtb] -> B-frags: K=128 (4 ks), N=256 (16 nt) ----------------
// nt: m = nt>>2 (matrix), col-in-matrix = (nt&3)*16 + (lane&15)
__global__ void prep_wgf(const float* __restrict__ Wff1, const float* __restrict__ Wff2,
                         const float* __restrict__ Wta,  const float* __restrict__ Wtb,
                         unsigned short* __restrict__ wgf) {
    int i = blockIdx.x * blockDim.x + threadIdx.x;   // 32768
    int j = i & 7, lane = (i >> 3) & 63, nt = (i >> 9) & 15, kstep = (i >> 13) & 3;
    int k = kstep * 32 + ((lane >> 4) & 3) * 8 + j;          // z dim 0..127
    int m = nt >> 2;
    int c = (nt & 3) * 16 + (lane & 15);                      // col 0..63
    const float* Wm = (m == 0) ? Wff1 : (m == 1) ? Wff2 : (m == 2) ? Wta : Wtb;
    wgf[i] = f2bf(Wm[k * 64 + c]);
}

// ---------------- conv1 as implicit GEMM, bf16 MFMA ----------------
__global__ __launch_bounds__(256) void conv1_mfma(const float* __restrict__ x,
                                                  const float* __restrict__ b1,
                                                  const unsigned short* __restrict__ w1f,
                                                  unsigned short* __restrict__ h1b) {
    __shared__ unsigned int xs32[3 * 2046];        // 24.6 KB
    int img = blockIdx.x;
    int tid = threadIdx.x;
    const float* xg = x + (size_t)img * 11532;
    for (int d = tid; d < 5766; d += 256) {
        int c = d / 1922, r = d - c * 1922;
        int y = r / 31, xd = r - y * 31;
        const float* s = xg + c * 3844 + y * 62 + xd * 2;
        unsigned int lo = f2bf(s[0]), hi = f2bf(s[1]);
        xs32[c * 2046 + y * 33 + xd] = lo | (hi << 16);
    }
    __syncthreads();

    int lane = tid & 63, wid = tid >> 6;
    int rowl = lane & 15, g = lane >> 4;

    short8 bfr[2][2];
    #pragma unroll
    for (int ks = 0; ks < 2; ++ks)
        #pragma unroll
        for (int nt = 0; nt < 2; ++nt)
            bfr[ks][nt] = *(const short8*)(w1f + (((ks * 2 + nt) * 64 + lane) << 3));
    float bias0 = b1[rowl], bias1 = b1[16 + rowl];

    for (int i = 0; i < 15; ++i) {
        int mtile = wid + 4 * i;
        if (mtile >= 57) break;
        int m = mtile * 16 + rowl; if (m > 899) m = 899;
        int oy = m / 30, ox = m - oy * 30;
        int dof = (2 * oy + g) * 33 + ox;
        union { unsigned int u[4]; short8 s; } af0, af1;
        af0.u[0] = xs32[dof];          af0.u[1] = xs32[dof + 1];
        af0.u[2] = xs32[2046 + dof];   af0.u[3] = xs32[2046 + dof + 1];
        af1.u[0] = xs32[4092 + dof];   af1.u[1] = xs32[4092 + dof + 1];
        af1.u[2] = 0;                  af1.u[3] = 0;
        f32x4 acc0 = (f32x4){0.f, 0.f, 0.f, 0.f};
        f32x4 acc1 = (f32x4){0.f, 0.f, 0.f, 0.f};
        acc0 = __builtin_amdgcn_mfma_f32_16x16x32_bf16(af0.s, bfr[0][0], acc0, 0, 0, 0);
        acc0 = __builtin_amdgcn_mfma_f32_16x16x32_bf16(af1.s, bfr[1][0], acc0, 0, 0, 0);
        acc1 = __builtin_amdgcn_mfma_f32_16x16x32_bf16(af0.s, bfr[0][1], acc1, 0, 0, 0);
        acc1 = __builtin_amdgcn_mfma_f32_16x16x32_bf16(af1.s, bfr[1][1], acc1, 0, 0, 0);
        int sp0 = mtile * 16 + g * 4;
        #pragma unroll
        for (int nt = 0; nt < 2; ++nt) {
            f32x4 a = nt ? acc1 : acc0;
            int oc = nt * 16 + rowl;
            float bias = nt ? bias1 : bias0;
            unsigned short pk[4];
            #pragma unroll
            for (int r = 0; r < 4; ++r) pk[r] = f2bf(fmaxf(a[r] + bias, 0.f));
            unsigned short* dstp = h1b + (size_t)img * 28800 + oc * 900 + sp0;
            if (sp0 + 3 < 900) {
                *(uint2*)dstp = *(uint2*)pk;
            } else {
                #pragma unroll
                for (int r = 0; r < 4; ++r) if (sp0 + r < 900) dstp[r] = pk[r];
            }
        }
    }
}

// ---------------- conv2 as implicit GEMM, bf16 MFMA ----------------
__global__ __launch_bounds__(256) void conv2_mfma(const unsigned short* __restrict__ h1b,
                                                  const float* __restrict__ b2,
                                                  const unsigned short* __restrict__ w2f,
                                                  unsigned short* __restrict__ featb) {
    __shared__ unsigned short h1s[32 * 30 * 32];   // [ic][y][x pad 32] = 60 KB
    int img = blockIdx.x;
    int tid = threadIdx.x;
    {
        const unsigned int* src = (const unsigned int*)(h1b + (size_t)img * 28800);
        unsigned int* dst = (unsigned int*)h1s;
        for (int d = tid; d < 14400; d += 256) {
            int ic = d / 450, r = d - ic * 450;
            int y = r / 15, x2 = r - y * 15;
            dst[(ic * 30 + y) * 16 + x2] = src[d];
        }
    }
    __syncthreads();
    int lane = tid & 63, wid = tid >> 6;
    int rowl = lane & 15, g = lane >> 4;

    f32x4 acc[4][4];
    #pragma unroll
    for (int i = 0; i < 4; ++i)
        #pragma unroll
        for (int nt = 0; nt < 4; ++nt) acc[i][nt] = (f32x4){0.f, 0.f, 0.f, 0.f};

    int dofs[4];
    #pragma unroll
    for (int i = 0; i < 4; ++i) {
        int mtile = wid + 4 * i;
        int m = mtile * 16 + rowl; if (m > 195) m = 195;
        int oy = m / 14, ox = m - oy * 14;
        int y = 2 * oy + g, x0 = 2 * ox;
        dofs[i] = y * 16 + (x0 >> 1);
    }
    const unsigned int* lds32 = (const unsigned int*)h1s;

    #pragma unroll 4
    for (int kstep = 0; kstep < 16; ++kstep) {
        short8 bfr[4];
        #pragma unroll
        for (int nt = 0; nt < 4; ++nt)
            bfr[nt] = *(const short8*)(w2f + (((nt * 16 + kstep) * 64 + lane) << 3));
        int icb = kstep * 960;
        #pragma unroll
        for (int i = 0; i < 4; ++i) {
            int mtile = wid + 4 * i;
            if (mtile < 13) {
                int dof = icb + dofs[i];
                union { unsigned int u[4]; short8 s; } af;
                af.u[0] = lds32[dof];
                af.u[1] = lds32[dof + 1];
                af.u[2] = lds32[dof + 480];
                af.u[3] = lds32[dof + 481];
                #pragma unroll
                for (int nt = 0; nt < 4; ++nt)
                    acc[i][nt] = __builtin_amdgcn_mfma_f32_16x16x32_bf16(af.s, bfr[nt], acc[i][nt], 0, 0, 0);
            }
        }
    }
    #pragma unroll
    for (int i = 0; i < 4; ++i) {
        int mtile = wid + 4 * i;
        if (mtile >= 13) continue;
        int sp0 = mtile * 16 + g * 4;
        #pragma unroll
        for (int nt = 0; nt < 4; ++nt) {
            int oc = nt * 16 + rowl;
            float bias = b2[oc];
            unsigned short pk[4];
            #pragma unroll
            for (int r = 0; r < 4; ++r)
                pk[r] = f2bf(fmaxf(acc[i][nt][r] + bias, 0.f));
            unsigned short* dstp = featb + (size_t)img * 12544 + oc * 196 + sp0;
            if (sp0 + 3 < 196) {
                *(uint2*)dstp = *(uint2*)pk;
            } else {
                #pragma unroll
                for (int r = 0; r < 4; ++r) if (sp0 + r < 196) dstp[r] = pk[r];
            }
        }
    }
}

// ---------------- u = feat @ W_in : bf16 MFMA, split-K=28 ----------------
__global__ __launch_bounds__(256) void gemm_u_mfma(const unsigned short* __restrict__ featb,
                                                   const unsigned short* __restrict__ Wbbf,
                                                   float* __restrict__ part) {
    int tid = threadIdx.x, lane = tid & 63, wid = tid >> 6;
    int rowl = lane & 15, g = lane >> 4;
    int m0 = blockIdx.x * 64 + wid * 16;
    int ks0 = blockIdx.y * 14;
    f32x4 acc[8];
    #pragma unroll
    for (int nt = 0; nt < 8; ++nt) acc[nt] = (f32x4){0.f, 0.f, 0.f, 0.f};
    const unsigned short* arow = featb + (size_t)(m0 + rowl) * FEATN + g * 8;
    #pragma unroll 2
    for (int kk = 0; kk < 14; ++kk) {
        int kstep = ks0 + kk;
        short8 afr = *(const short8*)(arow + kstep * 32);
        #pragma unroll
        for (int nt = 0; nt < 8; ++nt) {
            short8 bfr = *(const short8*)(Wbbf + ((((size_t)kstep * 8 + nt) * 64 + lane) << 3));
            acc[nt] = __builtin_amdgcn_mfma_f32_16x16x32_bf16(afr, bfr, acc[nt], 0, 0, 0);
        }
    }
    float* pg = part + (size_t)blockIdx.y * 131072;
    #pragma unroll
    for (int nt = 0; nt < 8; ++nt)
        #pragma unroll
        for (int r = 0; r < 4; ++r)
            pg[(m0 + g * 4 + r) * 128 + nt * 16 + rowl] = acc[nt][r];
}

// reduce into u laid out [t][b][128]
__global__ void reduce_u(const float* __restrict__ part, const float* __restrict__ bbb,
                         float* __restrict__ u) {
    int o = blockIdx.x * 256 + threadIdx.x;   // 131072 total
    int c = o & 127, b = (o >> 7) & 15, t = o >> 11;
    int m = b * 64 + t;
    float s = bbb[c];
    #pragma unroll
    for (int ks = 0; ks < 28; ++ks) s += part[(size_t)ks * 131072 + m * 128 + c];
    u[o] = s;
}

// ---------------- liquid RNN scan: batched MFMA (M=16 batches), 1 block ----------------
// Phase1: z[16][128] = lecun_tanh(u_t + hid@Wh)  (wave w: cols 32w..32w+31)
// Phase2: [ff1|ff2|ta|tb][16][64] = z @ Wg        (wave w: cols 16w..16w+15 of each matrix)
// hid and z pass through MFMA as split-bf16 (hi+lo) => near-f32 A-operands.
// LDS arrays XOR-swizzled: byte ^= (row&7)<<4 on BOTH write and read.
__global__ __launch_bounds__(256, 1) void rnn_mfma(const float* __restrict__ u,
                                                   const unsigned short* __restrict__ whf,
                                                   const unsigned short* __restrict__ wgf,
                                                   const float* __restrict__ bff1,
                                                   const float* __restrict__ bff2,
                                                   const float* __restrict__ bta,
                                                   const float* __restrict__ btb,
                                                   float* __restrict__ hid_out) {
    __shared__ unsigned short hidA_hi[16 * 64], hidA_lo[16 * 64];   // [row][k0..63], 128B rows
    __shared__ unsigned short zA_hi[16 * 128], zA_lo[16 * 128];     // [row][k0..127], 256B rows
    int tid = threadIdx.x, lane = tid & 63, w = tid >> 6;
    int rowl = lane & 15, g = lane >> 4;

    for (int idx = tid; idx < 1024; idx += 256) { hidA_hi[idx] = 0; hidA_lo[idx] = 0; }

    // B-fragments -> registers (once)
    short8 wh_r[2][2];   // [kstep][ntl], nt_abs = 2w + ntl
    #pragma unroll
    for (int ks = 0; ks < 2; ++ks)
        #pragma unroll
        for (int ntl = 0; ntl < 2; ++ntl)
            wh_r[ks][ntl] = *(const short8*)(whf + (((ks * 8 + 2 * w + ntl) * 64 + lane) << 3));
    short8 wg_r[4][4];   // [m][kstep], nt_abs = 4m + w
    #pragma unroll
    for (int m = 0; m < 4; ++m)
        #pragma unroll
        for (int ks = 0; ks < 4; ++ks)
            wg_r[m][ks] = *(const short8*)(wgf + (((ks * 16 + 4 * m + w) * 64 + lane) << 3));

    int cc = w * 16 + rowl;                   // this lane's phase-2 column
    float bias1 = bff1[cc], bias2 = bff2[cc], biast = bta[cc] + btb[cc];

    // u prefetch (t=0)
    float upf[8];
    #pragma unroll
    for (int i = 0; i < 8; ++i) {
        int ntl = i >> 2, r = i & 3;
        upf[i] = u[(g * 4 + r) * 128 + (2 * w + ntl) * 16 + rowl];
    }
    __syncthreads();

    float hidv[4];
    #pragma unroll 1
    for (int t = 0; t < 64; ++t) {
        // ---- Phase 1 ----
        short8 ah[2], al[2];
        #pragma unroll
        for (int ks = 0; ks < 2; ++ks) {
            int byte = (rowl * 128 + ks * 64 + g * 16) ^ ((rowl & 7) << 4);
            ah[ks] = *(const short8*)((const char*)hidA_hi + byte);
            al[ks] = *(const short8*)((const char*)hidA_lo + byte);
        }
        f32x4 zacc[2];
        #pragma unroll
        for (int ntl = 0; ntl < 2; ++ntl) {
            zacc[ntl] = (f32x4){upf[ntl * 4 + 0], upf[ntl * 4 + 1], upf[ntl * 4 + 2], upf[ntl * 4 + 3]};
            #pragma unroll
            for (int ks = 0; ks < 2; ++ks) {
                zacc[ntl] = __builtin_amdgcn_mfma_f32_16x16x32_bf16(al[ks], wh_r[ks][ntl], zacc[ntl], 0, 0, 0);
                zacc[ntl] = __builtin_amdgcn_mfma_f32_16x16x32_bf16(ah[ks], wh_r[ks][ntl], zacc[ntl], 0, 0, 0);
            }
        }
        // prefetch u for t+1 (overlaps rest of step)
        if (t < 63) {
            #pragma unroll
            for (int i = 0; i < 8; ++i) {
                int ntl = i >> 2, r = i & 3;
                upf[i] = u[(t + 1) * 2048 + (g * 4 + r) * 128 + (2 * w + ntl) * 16 + rowl];
            }
        }
        // tanh + write z (hi/lo) to LDS
        #pragma unroll
        for (int ntl = 0; ntl < 2; ++ntl)
            #pragma unroll
            for (int r = 0; r < 4; ++r) {
                float zv = 1.7159f * fast_tanh(0.666f * zacc[ntl][r]);
                int row = g * 4 + r, c = w * 32 + ntl * 16 + rowl;
                unsigned short zh = f2bf(zv);
                unsigned short zl = f2bf(zv - bf2f(zh));
                int byte = (row * 256 + c * 2) ^ ((row & 7) << 4);
                *(unsigned short*)((char*)zA_hi + byte) = zh;
                *(unsigned short*)((char*)zA_lo + byte) = zl;
            }
        __syncthreads();
        // ---- Phase 2 ----
        short8 zh[4], zl[4];
        #pragma unroll
        for (int ks = 0; ks < 4; ++ks) {
            int byte = (rowl * 256 + ks * 64 + g * 16) ^ ((rowl & 7) << 4);
            zh[ks] = *(const short8*)((const char*)zA_hi + byte);
            zl[ks] = *(const short8*)((const char*)zA_lo + byte);
        }
        f32x4 facc[4];
        facc[0] = (f32x4){bias1, bias1, bias1, bias1};
        facc[1] = (f32x4){bias2, bias2, bias2, bias2};
        facc[2] = (f32x4){biast, biast, biast, biast};
        facc[3] = (f32x4){0.f, 0.f, 0.f, 0.f};
        #pragma unroll
        for (int m = 0; m < 4; ++m)
            #pragma unroll
            for (int ks = 0; ks < 4; ++ks) {
                facc[m] = __builtin_amdgcn_mfma_f32_16x16x32_bf16(zl[ks], wg_r[m][ks], facc[m], 0, 0, 0);
                facc[m] = __builtin_amdgcn_mfma_f32_16x16x32_bf16(zh[ks], wg_r[m][ks], facc[m], 0, 0, 0);
            }
        // activations + hid (hi/lo) write
        #pragma unroll
        for (int r = 0; r < 4; ++r) {
            float ff1 = fast_tanh(facc[0][r]);
            float ff2 = fast_tanh(facc[1][r]);
            float tt  = fast_sigmoid(facc[2][r] + facc[3][r]);
            float hv  = ff1 * (1.f - tt) + tt * ff2;
            hidv[r] = hv;
            int row = g * 4 + r;
            unsigned short hh = f2bf(hv);
            unsigned short hl = f2bf(hv - bf2f(hh));
            int byte = (row * 128 + cc * 2) ^ ((row & 7) << 4);
            *(unsigned short*)((char*)hidA_hi + byte) = hh;
            *(unsigned short*)((char*)hidA_lo + byte) = hl;
        }
        __syncthreads();
    }
    #pragma unroll
    for (int r = 0; r < 4; ++r)
        hid_out[(g * 4 + r) * 64 + cc] = hidv[r];
}

// ---------------- head ----------------
__global__ void head_kernel(const float* __restrict__ hid, const float* __restrict__ Wout,
                            const float* __restrict__ bout, float* __restrict__ out) {
    int tid = threadIdx.x;           // 128 = 16*8
    int b = tid >> 3, a = tid & 7;
    float s = bout[a];
    #pragma unroll
    for (int j = 0; j < 64; ++j) s += hid[b * 64 + j] * Wout[j * 8 + a];
    out[tid] = s;
}

extern "C" void kernel_launch(void* const* d_in, const int* in_sizes, int n_in,
                              void* d_out, int out_size, void* d_ws, size_t ws_size,
                              hipStream_t stream) {
    const float* x    = (const float*)d_in[0];
    const float* w1   = (const float*)d_in[1];
    const float* b1   = (const float*)d_in[2];
    const float* w2   = (const float*)d_in[3];
    const float* b2   = (const float*)d_in[4];
    const float* Wbb  = (const float*)d_in[5];
    const float* bbb  = (const float*)d_in[6];
    const float* Wff1 = (const float*)d_in[7];
    const float* bff1 = (const float*)d_in[8];
    const float* Wff2 = (const float*)d_in[9];
    const float* bff2 = (const float*)d_in[10];
    const float* Wta  = (const float*)d_in[11];
    const float* bta  = (const float*)d_in[12];
    const float* Wtb  = (const float*)d_in[13];
    const float* btb  = (const float*)d_in[14];
    const float* Wout = (const float*)d_in[15];
    const float* bout = (const float*)d_in[16];

    if (ws_size < (size_t)WS_BYTES) return;

    char* wsb = (char*)d_ws;
    unsigned short* w1f   = (unsigned short*)(wsb + OFF_W1F);
    unsigned short* w2f   = (unsigned short*)(wsb + OFF_W2F);
    unsigned short* wbbf  = (unsigned short*)(wsb + OFF_WBBF);
    unsigned short* h1b   = (unsigned short*)(wsb + OFF_H1B);
    unsigned short* featb = (unsigned short*)(wsb + OFF_FEATB);
    float*          u     = (float*)(wsb + OFF_U);
    float*          part  = (float*)(wsb + OFF_PART);
    float*          hid   = (float*)(wsb + OFF_HID);
    unsigned short* whf   = (unsigned short*)(wsb + OFF_WHF);
    unsigned short* wgf   = (unsigned short*)(wsb + OFF_WGF);

    prep_w1f <<<8, 256, 0, stream>>>(w1, w1f);
    prep_w2f <<<128, 256, 0, stream>>>(w2, w2f);
    prep_wbbf<<<6272, 256, 0, stream>>>(Wbb, wbbf);
    prep_whf <<<32, 256, 0, stream>>>(Wbb, whf);
    prep_wgf <<<128, 256, 0, stream>>>(Wff1, Wff2, Wta, Wtb, wgf);
    conv1_mfma<<<1024, 256, 0, stream>>>(x, b1, w1f, h1b);
    conv2_mfma<<<1024, 256, 0, stream>>>(h1b, b2, w2f, featb);
    gemm_u_mfma<<<dim3(16, 28), 256, 0, stream>>>(featb, wbbf, part);
    reduce_u<<<512, 256, 0, stream>>>(part, bbb, u);
    rnn_mfma<<<1, 256, 0, stream>>>(u, whf, wgf, bff1, bff2, bta, btb, hid);
    head_kernel<<<1, 128, 0, stream>>>(hid, Wout, bout, (float*)d_out);
}